// Round 1
// baseline (3210.290 us; speedup 1.0000x reference)
//
#include <hip/hip_runtime.h>
#include <hip/hip_bf16.h>

#define D 128
#define DE 32
#define RNUM 16
#define BNUM 8
#define APAD 132
#define EPB 16

// ---------------- w_rel[r] = sum_b comp[r,b] * weight[b] ----------------
__global__ void k_wrel(const float* __restrict__ comp, const float* __restrict__ weight,
                       float* __restrict__ wrel) {
    int idx = blockIdx.x * blockDim.x + threadIdx.x;
    int total = RNUM * D * D;
    int stride = gridDim.x * blockDim.x;
    for (; idx < total; idx += stride) {
        int r = idx >> 14;          // / (128*128)
        int rest = idx & 16383;
        float s = 0.f;
#pragma unroll
        for (int b = 0; b < BNUM; ++b) s += comp[r * BNUM + b] * weight[b * 16384 + rest];
        wrel[idx] = s;
    }
}

// ---------------- attention alphas for edges 0..15 only ----------------
__global__ void k_alphas(const float* __restrict__ vfts, const int* __restrict__ adjs,
                         const float* __restrict__ er, const float* __restrict__ ert,
                         const float* __restrict__ w1, const float* __restrict__ b1,
                         const float* __restrict__ w2, const float* __restrict__ b2,
                         float* __restrict__ alphas, int E) {
    __shared__ float erps[2 * D + 2 * DE];
    __shared__ float red[D];
    int e = blockIdx.x, t = threadIdx.x;
    int src = adjs[e], dst = adjs[E + e];
    erps[t] = vfts[src * D + t];
    erps[D + t] = vfts[dst * D + t];
    if (t < DE) {
        erps[2 * D + t] = er[e * DE + t];
        erps[2 * D + DE + t] = ert[e * DE + t];
    }
    __syncthreads();
    float h = b1[t];
    for (int k = 0; k < 2 * D + 2 * DE; ++k) h += erps[k] * w1[k * D + t];
    h = fmaxf(h, 0.f);
    red[t] = h * w2[t];
    __syncthreads();
    for (int s = 64; s > 0; s >>= 1) {
        if (t < s) red[t] += red[t + s];
        __syncthreads();
    }
    if (t == 0) alphas[e] = 1.f / (1.f + expf(-(red[0] + b2[0])));
}

// ---------------- count per-relation edges + node in-degree ----------------
__global__ void k_count(const int* __restrict__ adjs, const int* __restrict__ rels, int E,
                        int* __restrict__ cnt, int* __restrict__ indeg) {
    int gid = blockIdx.x * blockDim.x + threadIdx.x;
    int total = gridDim.x * blockDim.x;
    int lane = threadIdx.x & 63;
    int iters = (E + total - 1) / total;
    for (int it = 0; it < iters; ++it) {
        int i = it * total + gid;
        bool valid = i < E;
        int r = valid ? rels[i] : -1;
        if (valid) atomicAdd(&indeg[adjs[E + i]], 1);
#pragma unroll
        for (int rr = 0; rr < RNUM; ++rr) {
            unsigned long long m = __ballot(r == rr);
            if (r == rr) {
                int leader = __ffsll((unsigned long long)m) - 1;
                if (lane == leader) atomicAdd(&cnt[rr], __popcll(m));
            }
        }
    }
}

__global__ void k_prefix(const int* __restrict__ cnt, int* __restrict__ basep,
                         int* __restrict__ pos) {
    if (threadIdx.x == 0) {
        int s = 0;
        for (int r = 0; r < RNUM; ++r) {
            basep[r] = s;
            pos[r] = s;
            s += cnt[r];
        }
        basep[RNUM] = s;
    }
}

// ---------------- counting-sort scatter of edge ids by relation ----------------
__global__ void k_scatter(const int* __restrict__ rels, int E, int* __restrict__ pos,
                          int* __restrict__ sorted) {
    int gid = blockIdx.x * blockDim.x + threadIdx.x;
    int total = gridDim.x * blockDim.x;
    int lane = threadIdx.x & 63;
    int iters = (E + total - 1) / total;
    for (int it = 0; it < iters; ++it) {
        int i = it * total + gid;
        bool valid = i < E;
        int r = valid ? rels[i] : -1;
#pragma unroll
        for (int rr = 0; rr < RNUM; ++rr) {
            unsigned long long m = __ballot(r == rr);
            if (r == rr) {
                int leader = __ffsll((unsigned long long)m) - 1;
                int c = __popcll(m);
                int base = 0;
                if (lane == leader) base = atomicAdd(&pos[rr], c);
                base = __shfl(base, leader, 64);
                int rank = __popcll(m & ((1ull << lane) - 1ull));
                sorted[base + rank] = i;
            }
        }
    }
}

// ---------------- out[n] = indeg[n] * (vfts[n] @ update) ----------------
#define INIT_NODES 16
__global__ void k_init(const float* __restrict__ vfts, const float* __restrict__ update,
                       const int* __restrict__ indeg, float* __restrict__ out, int N) {
    __shared__ float upd[D * D];               // 64 KB
    __shared__ float rows[INIT_NODES][APAD];   // ~8.25 KB
    int t = threadIdx.x;
    for (int idx = t; idx < D * D; idx += 256) upd[idx] = update[idx];
    int g = t >> 5;       // 0..7, handles 2 nodes
    int cg = t & 31;      // 4 cols
    for (int nb = blockIdx.x * INIT_NODES; nb < N; nb += gridDim.x * INIT_NODES) {
        __syncthreads();
        for (int idx = t; idx < INIT_NODES * D; idx += 256) {
            int nn = idx >> 7, k = idx & 127;
            int n = nb + nn;
            rows[nn][k] = (n < N) ? vfts[n * D + k] : 0.f;
        }
        __syncthreads();
        int n0 = g * 2, n1 = g * 2 + 1;
        float acc0[4] = {0, 0, 0, 0}, acc1[4] = {0, 0, 0, 0};
#pragma unroll 4
        for (int k = 0; k < D; ++k) {
            float4 w = *(const float4*)&upd[k * D + cg * 4];
            float a0 = rows[n0][k], a1 = rows[n1][k];
            acc0[0] += a0 * w.x; acc0[1] += a0 * w.y; acc0[2] += a0 * w.z; acc0[3] += a0 * w.w;
            acc1[0] += a1 * w.x; acc1[1] += a1 * w.y; acc1[2] += a1 * w.z; acc1[3] += a1 * w.w;
        }
        int na = nb + n0, nc = nb + n1;
        if (na < N) {
            float deg = (float)indeg[na];
            *(float4*)&out[na * D + cg * 4] =
                make_float4(deg * acc0[0], deg * acc0[1], deg * acc0[2], deg * acc0[3]);
        }
        if (nc < N) {
            float deg = (float)indeg[nc];
            *(float4*)&out[nc * D + cg * 4] =
                make_float4(deg * acc1[0], deg * acc1[1], deg * acc1[2], deg * acc1[3]);
        }
    }
}

// ---------------- per-relation edge GEMM + atomic scatter-add ----------------
__global__ void k_edge(const float* __restrict__ vfts, const int* __restrict__ adjs,
                       const float* __restrict__ wrel, const float* __restrict__ alphas,
                       const int* __restrict__ basep, const int* __restrict__ sorted,
                       float* __restrict__ out, int E, int P) {
    __shared__ float wlds[D * D];          // 64 KB
    __shared__ float alds[EPB][APAD];      // ~8.25 KB
    __shared__ int esrc[EPB], edst[EPB];
    int t = threadIdx.x;
    int r = blockIdx.x / P;
    int bp = blockIdx.x % P;
    for (int idx = t; idx < D * D / 4; idx += 256)
        ((float4*)wlds)[idx] = ((const float4*)(wrel + r * D * D))[idx];
    float alpha = alphas[r];
    int s0 = basep[r], s1 = basep[r + 1];
    int g = t >> 5;   // 0..7 -> edges g*2, g*2+1
    int cg = t & 31;  // cols cg*4..+3
    for (int off = s0 + bp * EPB; off < s1; off += P * EPB) {
        __syncthreads();
        if (t < EPB) {
            int idx = off + t;
            if (idx < s1) {
                int eid = sorted[idx];
                esrc[t] = adjs[eid];
                edst[t] = adjs[E + eid];
            } else {
                esrc[t] = 0;
                edst[t] = -1;
            }
        }
        __syncthreads();
        for (int idx = t; idx < EPB * D; idx += 256) {
            int e = idx >> 7, k = idx & 127;
            alds[e][k] = vfts[esrc[e] * D + k];
        }
        __syncthreads();
        int e0 = g * 2, e1 = e0 + 1;
        float acc0[4] = {0, 0, 0, 0}, acc1[4] = {0, 0, 0, 0};
#pragma unroll 4
        for (int k = 0; k < D; ++k) {
            float4 w = *(const float4*)&wlds[k * D + cg * 4];
            float a0 = alds[e0][k], a1 = alds[e1][k];
            acc0[0] += a0 * w.x; acc0[1] += a0 * w.y; acc0[2] += a0 * w.z; acc0[3] += a0 * w.w;
            acc1[0] += a1 * w.x; acc1[1] += a1 * w.y; acc1[2] += a1 * w.z; acc1[3] += a1 * w.w;
        }
        int d0 = edst[e0], d1 = edst[e1];
        if (d0 >= 0) {
            float* p = out + d0 * D + cg * 4;
            atomicAdd(p + 0, alpha * acc0[0]);
            atomicAdd(p + 1, alpha * acc0[1]);
            atomicAdd(p + 2, alpha * acc0[2]);
            atomicAdd(p + 3, alpha * acc0[3]);
        }
        if (d1 >= 0) {
            float* p = out + d1 * D + cg * 4;
            atomicAdd(p + 0, alpha * acc1[0]);
            atomicAdd(p + 1, alpha * acc1[1]);
            atomicAdd(p + 2, alpha * acc1[2]);
            atomicAdd(p + 3, alpha * acc1[3]);
        }
    }
}

__global__ void k_relu(float* __restrict__ out, int total4) {
    int i = blockIdx.x * blockDim.x + threadIdx.x;
    int stride = gridDim.x * blockDim.x;
    for (; i < total4; i += stride) {
        float4 v = ((float4*)out)[i];
        v.x = fmaxf(v.x, 0.f);
        v.y = fmaxf(v.y, 0.f);
        v.z = fmaxf(v.z, 0.f);
        v.w = fmaxf(v.w, 0.f);
        ((float4*)out)[i] = v;
    }
}

extern "C" void kernel_launch(void* const* d_in, const int* in_sizes, int n_in,
                              void* d_out, int out_size, void* d_ws, size_t ws_size,
                              hipStream_t stream) {
    const float* vfts   = (const float*)d_in[0];
    const int*   adjs   = (const int*)d_in[1];
    const int*   rels   = (const int*)d_in[2];
    const float* er     = (const float*)d_in[3];
    const float* ert    = (const float*)d_in[4];
    const float* weight = (const float*)d_in[5];
    const float* comp   = (const float*)d_in[6];
    const float* w1     = (const float*)d_in[7];
    const float* b1     = (const float*)d_in[8];
    const float* w2     = (const float*)d_in[9];
    const float* b2     = (const float*)d_in[10];
    const float* update = (const float*)d_in[11];
    float* out = (float*)d_out;

    int N = in_sizes[0] / D;
    int E = in_sizes[2];

    char* ws = (char*)d_ws;
    float* wrel   = (float*)ws;                       // 1 MB
    float* alphas = (float*)(ws + (1 << 20));         // 64 B
    int* ibase = (int*)(ws + (1 << 20) + 256);
    int* cnt   = ibase;                               // 16
    int* basep = ibase + 16;                          // 17 (padded to 32)
    int* pos   = ibase + 48;                          // 16
    int* indeg = ibase + 64;                          // N
    int* sorted = ibase + 64 + ((N + 63) & ~63);      // E

    // zero cnt/basep/pos/indeg in one shot
    hipMemsetAsync(cnt, 0, (64 + ((N + 63) & ~63)) * sizeof(int), stream);

    k_wrel<<<256, 256, 0, stream>>>(comp, weight, wrel);
    k_alphas<<<RNUM, D, 0, stream>>>(vfts, adjs, er, ert, w1, b1, w2, b2, alphas, E);
    k_count<<<256, 256, 0, stream>>>(adjs, rels, E, cnt, indeg);
    k_prefix<<<1, 64, 0, stream>>>(cnt, basep, pos);
    k_scatter<<<256, 256, 0, stream>>>(rels, E, pos, sorted);
    k_init<<<512, 256, 0, stream>>>(vfts, update, indeg, out, N);
    const int P = 32;
    k_edge<<<RNUM * P, 256, 0, stream>>>(vfts, adjs, wrel, alphas, basep, sorted, out, E, P);
    k_relu<<<512, 256, 0, stream>>>(out, N * D / 4);
}

// Round 5
// 420.448 us; speedup vs baseline: 7.6354x; 7.6354x over previous
//
#include <hip/hip_runtime.h>
#include <hip/hip_bf16.h>

#define D 128
#define DE 32
#define RNUM 16
#define BNUM 8
#define APAD 132
#define EPB 32       // edges per k_edge tile
#define NBLK 256     // blocks for hist/scatter passes
#define PPART 32     // partitions per relation in k_edge

typedef __attribute__((ext_vector_type(8))) short bfrag8;   // 8 bf16 in 4 VGPRs
typedef __attribute__((ext_vector_type(4))) float facc4;

__device__ inline unsigned short f2bf(float f) {
    union { float f; unsigned int u; } v; v.f = f;
    unsigned int u = v.u + 0x7FFFu + ((v.u >> 16) & 1u);   // RNE
    return (unsigned short)(u >> 16);
}

// ---------------- w_rel[r] = sum_b comp[r,b] * weight[b] ----------------
__global__ void k_wrel(const float* __restrict__ comp, const float* __restrict__ weight,
                       float* __restrict__ wrel) {
    int idx = blockIdx.x * blockDim.x + threadIdx.x;
    int total = RNUM * D * D;
    int stride = gridDim.x * blockDim.x;
    for (; idx < total; idx += stride) {
        int r = idx >> 14;
        int rest = idx & 16383;
        float s = 0.f;
#pragma unroll
        for (int b = 0; b < BNUM; ++b) s += comp[r * BNUM + b] * weight[b * 16384 + rest];
        wrel[idx] = s;
    }
}

// ---------------- attention alphas for edges 0..15 only ----------------
__global__ void k_alphas(const float* __restrict__ vfts, const int* __restrict__ adjs,
                         const float* __restrict__ er, const float* __restrict__ ert,
                         const float* __restrict__ w1, const float* __restrict__ b1,
                         const float* __restrict__ w2, const float* __restrict__ b2,
                         float* __restrict__ alphas, int E) {
    __shared__ float erps[2 * D + 2 * DE];
    __shared__ float red[D];
    int e = blockIdx.x, t = threadIdx.x;
    int src = adjs[e], dst = adjs[E + e];
    erps[t] = vfts[src * D + t];
    erps[D + t] = vfts[dst * D + t];
    if (t < DE) {
        erps[2 * D + t] = er[e * DE + t];
        erps[2 * D + DE + t] = ert[e * DE + t];
    }
    __syncthreads();
    float h = b1[t];
    for (int k = 0; k < 2 * D + 2 * DE; ++k) h += erps[k] * w1[k * D + t];
    h = fmaxf(h, 0.f);
    red[t] = h * w2[t];
    __syncthreads();
    for (int s = 64; s > 0; s >>= 1) {
        if (t < s) red[t] += red[t + s];
        __syncthreads();
    }
    if (t == 0) alphas[e] = 1.f / (1.f + expf(-(red[0] + b2[0])));
}

// ---------------- pass A: per-block relation histogram + node in-degree ----------------
__global__ void k_hist(const int* __restrict__ adjs, const int* __restrict__ rels, int E,
                       int* __restrict__ blockHist, int* __restrict__ indeg) {
    __shared__ int h[4][RNUM];
    int t = threadIdx.x;
    if (t < 4 * RNUM) ((int*)h)[t] = 0;
    __syncthreads();
    int w = t >> 6;
    int chunk = (E + NBLK - 1) / NBLK;
    int start = blockIdx.x * chunk;
    int end = min(start + chunk, E);
    for (int i = start + t; i < end; i += 256) {
        atomicAdd(&h[w][rels[i]], 1);
        atomicAdd(&indeg[adjs[E + i]], 1);
    }
    __syncthreads();
    if (t < RNUM)
        blockHist[blockIdx.x * RNUM + t] = h[0][t] + h[1][t] + h[2][t] + h[3][t];
}

// ---------------- pass B: prefix sums -> basep[17], blockBase[NBLK][16] ----------------
__global__ void k_prefix2(const int* __restrict__ blockHist, int* __restrict__ basep,
                          int* __restrict__ blockBase) {
    __shared__ int hist[NBLK * RNUM];
    __shared__ int pre[NBLK * RNUM];
    __shared__ int bp[RNUM + 1];
    int t = threadIdx.x;
    for (int i = t; i < NBLK * RNUM; i += 256) hist[i] = blockHist[i];
    __syncthreads();
    if (t < RNUM) {
        int s = 0;
        for (int b = 0; b < NBLK; ++b) {
            pre[b * RNUM + t] = s;
            s += hist[b * RNUM + t];
        }
        bp[t] = s;
    }
    __syncthreads();
    if (t == 0) {
        int s = 0;
        for (int r = 0; r < RNUM; ++r) {
            int c = bp[r];
            bp[r] = s;
            basep[r] = s;
            s += c;
        }
        bp[RNUM] = s;
        basep[RNUM] = s;
    }
    __syncthreads();
    for (int i = t; i < NBLK * RNUM; i += 256)
        blockBase[i] = pre[i] + bp[i & (RNUM - 1)];
}

// ---------------- pass C: scatter edge ids into relation-sorted order ----------------
__global__ void k_scatter2(const int* __restrict__ rels, int E,
                           const int* __restrict__ blockBase, int* __restrict__ sorted) {
    __shared__ int pos[RNUM];
    int t = threadIdx.x;
    if (t < RNUM) pos[t] = blockBase[blockIdx.x * RNUM + t];
    __syncthreads();
    int chunk = (E + NBLK - 1) / NBLK;
    int start = blockIdx.x * chunk;
    int end = min(start + chunk, E);
    for (int i = start + t; i < end; i += 256) {
        int p = atomicAdd(&pos[rels[i]], 1);
        sorted[p] = i;
    }
}

// ---------------- out[n] = indeg[n] * (vfts[n] @ update) ----------------
#define INIT_NODES 16
__global__ void k_init(const float* __restrict__ vfts, const float* __restrict__ update,
                       const int* __restrict__ indeg, float* __restrict__ out, int N) {
    __shared__ float upd[D * D];
    __shared__ float rows[INIT_NODES][APAD];
    int t = threadIdx.x;
    for (int idx = t; idx < D * D; idx += 256) upd[idx] = update[idx];
    int g = t >> 5;
    int cg = t & 31;
    for (int nb = blockIdx.x * INIT_NODES; nb < N; nb += gridDim.x * INIT_NODES) {
        __syncthreads();
        for (int idx = t; idx < INIT_NODES * D; idx += 256) {
            int nn = idx >> 7, k = idx & 127;
            int n = nb + nn;
            rows[nn][k] = (n < N) ? vfts[n * D + k] : 0.f;
        }
        __syncthreads();
        int n0 = g * 2, n1 = g * 2 + 1;
        float acc0[4] = {0, 0, 0, 0}, acc1[4] = {0, 0, 0, 0};
#pragma unroll 4
        for (int k = 0; k < D; ++k) {
            float4 w = *(const float4*)&upd[k * D + cg * 4];
            float a0 = rows[n0][k], a1 = rows[n1][k];
            acc0[0] += a0 * w.x; acc0[1] += a0 * w.y; acc0[2] += a0 * w.z; acc0[3] += a0 * w.w;
            acc1[0] += a1 * w.x; acc1[1] += a1 * w.y; acc1[2] += a1 * w.z; acc1[3] += a1 * w.w;
        }
        int na = nb + n0, nc = nb + n1;
        if (na < N) {
            float deg = (float)indeg[na];
            *(float4*)&out[na * D + cg * 4] =
                make_float4(deg * acc0[0], deg * acc0[1], deg * acc0[2], deg * acc0[3]);
        }
        if (nc < N) {
            float deg = (float)indeg[nc];
            *(float4*)&out[nc * D + cg * 4] =
                make_float4(deg * acc1[0], deg * acc1[1], deg * acc1[2], deg * acc1[3]);
        }
    }
}

// ---------------- per-relation MFMA edge GEMM + atomic scatter-add ----------------
// 512 threads = 8 waves. Wave w: edge-subtile mtile=w>>2 (16 edges),
// cols [ (w&3)*32, +32 ) as two 16-col MFMA chains. K=128 in 4 steps of 32.
// LDS: wt[col][k] bf16 (W_r^T, XOR-swizzled), at[e][k] bf16 (edges, swizzled).
__global__ void __launch_bounds__(512)
k_edge(const float* __restrict__ vfts, const int* __restrict__ adjs,
       const float* __restrict__ wrel, const float* __restrict__ alphas,
       const int* __restrict__ basep, const int* __restrict__ sorted,
       float* __restrict__ out, int E) {
    __shared__ unsigned short wt[D * D];      // 32 KB
    __shared__ unsigned short at[EPB * D];    // 8 KB
    __shared__ int esrc[EPB], edst[EPB];
    int t = threadIdx.x;
    int r = blockIdx.x / PPART;
    int bp = blockIdx.x % PPART;

    // stage W_r^T: wt[col][k] = wrel[r][k][col], bf16, byte ^= (col&7)<<4
    const float* wr = wrel + r * D * D;
    for (int i = t; i < D * D; i += 512) {
        int k = i >> 7, col = i & 127;
        int byte = (col << 8) + (k << 1);
        byte ^= (col & 7) << 4;
        *(unsigned short*)((char*)wt + byte) = f2bf(wr[i]);
    }
    float alpha = alphas[r];
    int s0 = basep[r], s1 = basep[r + 1];

    int lane = t & 63;
    int wave = t >> 6;
    int mtile = wave >> 2;            // 0..1
    int colbase = (wave & 3) << 5;    // 0,32,64,96
    int se = t >> 4;                  // staging: edge 0..31
    int skb = (t & 15) << 3;          // staging: k-base 0..120

    for (int off = s0 + bp * EPB; off < s1; off += PPART * EPB) {
        __syncthreads();
        if (t < EPB) {
            int idx = off + t;
            if (idx < s1) {
                int eid = sorted[idx];
                esrc[t] = adjs[eid];
                edst[t] = adjs[E + eid];
            } else {
                esrc[t] = 0;
                edst[t] = -1;
            }
        }
        __syncthreads();
        // stage A: 8 floats per thread -> one swizzled 16B LDS write
        {
            const float* sp = vfts + (size_t)esrc[se] * D + skb;
            float4 f0 = *(const float4*)sp;
            float4 f1 = *(const float4*)(sp + 4);
            bfrag8 v;
            v[0] = (short)f2bf(f0.x); v[1] = (short)f2bf(f0.y);
            v[2] = (short)f2bf(f0.z); v[3] = (short)f2bf(f0.w);
            v[4] = (short)f2bf(f1.x); v[5] = (short)f2bf(f1.y);
            v[6] = (short)f2bf(f1.z); v[7] = (short)f2bf(f1.w);
            int byte = (se << 8) + (skb << 1);
            byte ^= (se & 7) << 4;
            *(bfrag8*)((char*)at + byte) = v;
        }
        __syncthreads();

        facc4 acc0 = {0.f, 0.f, 0.f, 0.f}, acc1 = {0.f, 0.f, 0.f, 0.f};
        int eb = (mtile << 4) + (lane & 15);
        int c0 = colbase + (lane & 15);
        int c1 = c0 + 16;
#pragma unroll
        for (int kk = 0; kk < 4; ++kk) {
            int kbase = (kk << 5) + ((lane >> 4) << 3);
            int ab = ((eb << 8) + (kbase << 1)) ^ ((eb & 7) << 4);
            bfrag8 a = *(const bfrag8*)((char*)at + ab);
            int b0 = ((c0 << 8) + (kbase << 1)) ^ ((c0 & 7) << 4);
            bfrag8 bv0 = *(const bfrag8*)((char*)wt + b0);
            int b1 = ((c1 << 8) + (kbase << 1)) ^ ((c1 & 7) << 4);
            bfrag8 bv1 = *(const bfrag8*)((char*)wt + b1);
            acc0 = __builtin_amdgcn_mfma_f32_16x16x32_bf16(a, bv0, acc0, 0, 0, 0);
            acc1 = __builtin_amdgcn_mfma_f32_16x16x32_bf16(a, bv1, acc1, 0, 0, 0);
        }
        // scatter: C/D mapping col=lane&15, row=(lane>>4)*4+reg
        int ebase = (mtile << 4) + ((lane >> 4) << 2);
#pragma unroll
        for (int j = 0; j < 4; ++j) {
            int d = edst[ebase + j];
            if (d >= 0) {
                float* p = out + (size_t)d * D + c0;
                atomicAdd(p, alpha * acc0[j]);
                atomicAdd(p + 16, alpha * acc1[j]);
            }
        }
    }
}

__global__ void k_relu(float* __restrict__ out, int total4) {
    int i = blockIdx.x * blockDim.x + threadIdx.x;
    int stride = gridDim.x * blockDim.x;
    for (; i < total4; i += stride) {
        float4 v = ((float4*)out)[i];
        v.x = fmaxf(v.x, 0.f);
        v.y = fmaxf(v.y, 0.f);
        v.z = fmaxf(v.z, 0.f);
        v.w = fmaxf(v.w, 0.f);
        ((float4*)out)[i] = v;
    }
}

extern "C" void kernel_launch(void* const* d_in, const int* in_sizes, int n_in,
                              void* d_out, int out_size, void* d_ws, size_t ws_size,
                              hipStream_t stream) {
    const float* vfts   = (const float*)d_in[0];
    const int*   adjs   = (const int*)d_in[1];
    const int*   rels   = (const int*)d_in[2];
    const float* er     = (const float*)d_in[3];
    const float* ert    = (const float*)d_in[4];
    const float* weight = (const float*)d_in[5];
    const float* comp   = (const float*)d_in[6];
    const float* w1     = (const float*)d_in[7];
    const float* b1     = (const float*)d_in[8];
    const float* w2     = (const float*)d_in[9];
    const float* b2     = (const float*)d_in[10];
    const float* update = (const float*)d_in[11];
    float* out = (float*)d_out;

    int N = in_sizes[0] / D;
    int E = in_sizes[2];

    char* ws = (char*)d_ws;
    float* wrel   = (float*)ws;                              // 1 MB
    float* alphas = (float*)(ws + (1 << 20));                // 64 B
    int* ibase = (int*)(ws + (1 << 20) + 256);
    int* basep     = ibase;                                  // 32
    int* indeg     = ibase + 32;                             // N (rounded)
    int* blockHist = indeg + ((N + 63) & ~63);               // NBLK*16
    int* blockBase = blockHist + NBLK * RNUM;                // NBLK*16
    int* sorted    = blockBase + NBLK * RNUM;                // E

    hipMemsetAsync(indeg, 0, ((N + 63) & ~63) * sizeof(int), stream);

    k_wrel<<<256, 256, 0, stream>>>(comp, weight, wrel);
    k_alphas<<<RNUM, D, 0, stream>>>(vfts, adjs, er, ert, w1, b1, w2, b2, alphas, E);
    k_hist<<<NBLK, 256, 0, stream>>>(adjs, rels, E, blockHist, indeg);
    k_prefix2<<<1, 256, 0, stream>>>(blockHist, basep, blockBase);
    k_scatter2<<<NBLK, 256, 0, stream>>>(rels, E, blockBase, sorted);
    k_init<<<512, 256, 0, stream>>>(vfts, update, indeg, out, N);
    k_edge<<<RNUM * PPART, 512, 0, stream>>>(vfts, adjs, wrel, alphas, basep, sorted, out, E);
    k_relu<<<512, 256, 0, stream>>>(out, N * D / 4);
}

// Round 6
// 379.718 us; speedup vs baseline: 8.4544x; 1.1073x over previous
//
#include <hip/hip_runtime.h>
#include <hip/hip_bf16.h>

#define D 128
#define DE 32
#define RNUM 16
#define BNUM 8
#define APAD 132
#define EPB 32       // edges per k_edge tile
#define NBLK 256     // blocks for hist/scatter/scan passes
#define PPART 32     // partitions per relation in k_edge

typedef __attribute__((ext_vector_type(8))) short bfrag8;   // 8 bf16 in 4 VGPRs
typedef __attribute__((ext_vector_type(4))) float facc4;

__device__ inline unsigned short f2bf(float f) {
    union { float f; unsigned int u; } v; v.f = f;
    unsigned int u = v.u + 0x7FFFu + ((v.u >> 16) & 1u);   // RNE
    return (unsigned short)(u >> 16);
}
__device__ inline float bf2f(unsigned short h) {
    union { unsigned int u; float f; } v; v.u = ((unsigned int)h) << 16; return v.f;
}

// ---------------- w_rel[r] = sum_b comp[r,b] * weight[b] ----------------
__global__ void k_wrel(const float* __restrict__ comp, const float* __restrict__ weight,
                       float* __restrict__ wrel) {
    int idx = blockIdx.x * blockDim.x + threadIdx.x;
    int total = RNUM * D * D;
    int stride = gridDim.x * blockDim.x;
    for (; idx < total; idx += stride) {
        int r = idx >> 14;
        int rest = idx & 16383;
        float s = 0.f;
#pragma unroll
        for (int b = 0; b < BNUM; ++b) s += comp[r * BNUM + b] * weight[b * 16384 + rest];
        wrel[idx] = s;
    }
}

// ---------------- attention alphas for edges 0..15 only ----------------
__global__ void k_alphas(const float* __restrict__ vfts, const int* __restrict__ adjs,
                         const float* __restrict__ er, const float* __restrict__ ert,
                         const float* __restrict__ w1, const float* __restrict__ b1,
                         const float* __restrict__ w2, const float* __restrict__ b2,
                         float* __restrict__ alphas, int E) {
    __shared__ float erps[2 * D + 2 * DE];
    __shared__ float red[D];
    int e = blockIdx.x, t = threadIdx.x;
    int src = adjs[e], dst = adjs[E + e];
    erps[t] = vfts[src * D + t];
    erps[D + t] = vfts[dst * D + t];
    if (t < DE) {
        erps[2 * D + t] = er[e * DE + t];
        erps[2 * D + DE + t] = ert[e * DE + t];
    }
    __syncthreads();
    float h = b1[t];
    for (int k = 0; k < 2 * D + 2 * DE; ++k) h += erps[k] * w1[k * D + t];
    h = fmaxf(h, 0.f);
    red[t] = h * w2[t];
    __syncthreads();
    for (int s = 64; s > 0; s >>= 1) {
        if (t < s) red[t] += red[t + s];
        __syncthreads();
    }
    if (t == 0) alphas[e] = 1.f / (1.f + expf(-(red[0] + b2[0])));
}

// ---------------- vfts -> bf16 copy ----------------
__global__ void k_prep(const float* __restrict__ vfts, unsigned short* __restrict__ vb,
                       int total8) {
    int i = blockIdx.x * blockDim.x + threadIdx.x;
    int stride = gridDim.x * blockDim.x;
    for (; i < total8; i += stride) {
        float4 f0 = ((const float4*)vfts)[i * 2];
        float4 f1 = ((const float4*)vfts)[i * 2 + 1];
        bfrag8 v;
        v[0] = (short)f2bf(f0.x); v[1] = (short)f2bf(f0.y);
        v[2] = (short)f2bf(f0.z); v[3] = (short)f2bf(f0.w);
        v[4] = (short)f2bf(f1.x); v[5] = (short)f2bf(f1.y);
        v[6] = (short)f2bf(f1.z); v[7] = (short)f2bf(f1.w);
        ((bfrag8*)vb)[i] = v;
    }
}

// ---------------- pass A: per-block relation histogram + node in-degree ----------------
__global__ void k_hist(const int* __restrict__ adjs, const int* __restrict__ rels, int E,
                       int* __restrict__ blockHist, int* __restrict__ indeg) {
    __shared__ int h[4][RNUM];
    int t = threadIdx.x;
    if (t < 4 * RNUM) ((int*)h)[t] = 0;
    __syncthreads();
    int w = t >> 6;
    int chunk = (E + NBLK - 1) / NBLK;
    int start = blockIdx.x * chunk;
    int end = min(start + chunk, E);
    for (int i = start + t; i < end; i += 256) {
        atomicAdd(&h[w][rels[i]], 1);
        atomicAdd(&indeg[adjs[E + i]], 1);
    }
    __syncthreads();
    if (t < RNUM)
        blockHist[blockIdx.x * RNUM + t] = h[0][t] + h[1][t] + h[2][t] + h[3][t];
}

// ---------------- pass B: prefix sums -> basep[17], blockBase[NBLK][16] ----------------
__global__ void k_prefix2(const int* __restrict__ blockHist, int* __restrict__ basep,
                          int* __restrict__ blockBase) {
    __shared__ int hist[NBLK * RNUM];
    __shared__ int pre[NBLK * RNUM];
    __shared__ int bp[RNUM + 1];
    int t = threadIdx.x;
    for (int i = t; i < NBLK * RNUM; i += 256) hist[i] = blockHist[i];
    __syncthreads();
    if (t < RNUM) {
        int s = 0;
        for (int b = 0; b < NBLK; ++b) {
            pre[b * RNUM + t] = s;
            s += hist[b * RNUM + t];
        }
        bp[t] = s;
    }
    __syncthreads();
    if (t == 0) {
        int s = 0;
        for (int r = 0; r < RNUM; ++r) {
            int c = bp[r];
            bp[r] = s;
            basep[r] = s;
            s += c;
        }
        bp[RNUM] = s;
        basep[RNUM] = s;
    }
    __syncthreads();
    for (int i = t; i < NBLK * RNUM; i += 256)
        blockBase[i] = pre[i] + bp[i & (RNUM - 1)];
}

// ---------------- pass C: scatter edge ids into relation-sorted order ----------------
__global__ void k_scatter2(const int* __restrict__ rels, int E,
                           const int* __restrict__ blockBase, int* __restrict__ sorted) {
    __shared__ int pos[RNUM];
    int t = threadIdx.x;
    if (t < RNUM) pos[t] = blockBase[blockIdx.x * RNUM + t];
    __syncthreads();
    int chunk = (E + NBLK - 1) / NBLK;
    int start = blockIdx.x * chunk;
    int end = min(start + chunk, E);
    for (int i = start + t; i < end; i += 256) {
        int p = atomicAdd(&pos[rels[i]], 1);
        sorted[p] = i;
    }
}

// ---------------- indeg prefix scan (3 passes) -> dstbase[N+1], dpos ----------------
__global__ void k_scanA(const int* __restrict__ indeg, int N, int* __restrict__ chunkSum) {
    __shared__ int sc[256];
    int t = threadIdx.x;
    int chunk = (N + NBLK - 1) / NBLK;
    int n0 = blockIdx.x * chunk;
    int v = (t < chunk && n0 + t < N) ? indeg[n0 + t] : 0;
    sc[t] = v;
    __syncthreads();
    for (int s = 128; s > 0; s >>= 1) {
        if (t < s) sc[t] += sc[t + s];
        __syncthreads();
    }
    if (t == 0) chunkSum[blockIdx.x] = sc[0];
}

__global__ void k_scanB(const int* __restrict__ chunkSum, int* __restrict__ chunkBase,
                        int* __restrict__ dstbase, int N) {
    if (threadIdx.x == 0) {
        int s = 0;
        for (int b = 0; b < NBLK; ++b) {
            chunkBase[b] = s;
            s += chunkSum[b];
        }
        dstbase[N] = s;
    }
}

__global__ void k_scanC(const int* __restrict__ indeg, int N,
                        const int* __restrict__ chunkBase, int* __restrict__ dstbase,
                        int* __restrict__ dpos) {
    __shared__ int sc[256];
    int t = threadIdx.x;
    int chunk = (N + NBLK - 1) / NBLK;
    int n0 = blockIdx.x * chunk;
    bool valid = (t < chunk) && (n0 + t < N);
    int v = valid ? indeg[n0 + t] : 0;
    sc[t] = v;
    __syncthreads();
    for (int ofs = 1; ofs < 256; ofs <<= 1) {
        int x = (t >= ofs) ? sc[t - ofs] : 0;
        __syncthreads();
        sc[t] += x;
        __syncthreads();
    }
    if (valid) {
        int excl = chunkBase[blockIdx.x] + sc[t] - v;
        dstbase[n0 + t] = excl;
        dpos[n0 + t] = excl;
    }
}

// ---------------- dst-sorted position for each rel-sorted slot ----------------
__global__ void k_dstpos(const int* __restrict__ adjs, const int* __restrict__ sorted, int E,
                         int* __restrict__ dpos, int* __restrict__ possorted) {
    int i = blockIdx.x * blockDim.x + threadIdx.x;
    int stride = gridDim.x * blockDim.x;
    for (; i < E; i += stride) {
        int eid = sorted[i];
        int dst = adjs[E + eid];
        possorted[i] = atomicAdd(&dpos[dst], 1);
    }
}

// ---------------- phase 1: per-relation MFMA edge GEMM -> srcs16 (no atomics) ----------------
__global__ void __launch_bounds__(512)
k_edge(const unsigned short* __restrict__ vb, const int* __restrict__ adjs,
       const float* __restrict__ wrel, const float* __restrict__ alphas,
       const int* __restrict__ basep, const int* __restrict__ sorted,
       const int* __restrict__ possorted, unsigned short* __restrict__ srcs16, int E) {
    __shared__ unsigned short wt[D * D];      // 32 KB
    __shared__ unsigned short at[EPB * D];    // 8 KB
    __shared__ int esrc[EPB], epos[EPB];
    int t = threadIdx.x;
    int r = blockIdx.x / PPART;
    int bp = blockIdx.x % PPART;

    // stage W_r^T: wt[col][k] = wrel[r][k][col], bf16, byte ^= (col&7)<<4
    const float* wr = wrel + r * D * D;
    for (int i = t; i < D * D; i += 512) {
        int k = i >> 7, col = i & 127;
        int byte = (col << 8) + (k << 1);
        byte ^= (col & 7) << 4;
        *(unsigned short*)((char*)wt + byte) = f2bf(wr[i]);
    }
    float alpha = alphas[r];
    int s0 = basep[r], s1 = basep[r + 1];

    int lane = t & 63;
    int wave = t >> 6;
    int mtile = wave >> 2;            // 0..1
    int colbase = (wave & 3) << 5;    // 0,32,64,96
    int se = t >> 4;                  // staging: edge 0..31
    int skb = (t & 15) << 3;          // staging: k-base 0..120

    for (int off = s0 + bp * EPB; off < s1; off += PPART * EPB) {
        __syncthreads();
        if (t < EPB) {
            int idx = off + t;
            if (idx < s1) {
                int eid = sorted[idx];
                esrc[t] = adjs[eid];
                epos[t] = possorted[idx];
            } else {
                esrc[t] = 0;
                epos[t] = -1;
            }
        }
        __syncthreads();
        // stage A: 8 bf16 per thread -> one swizzled 16B LDS write
        {
            bfrag8 v = *(const bfrag8*)(vb + (size_t)esrc[se] * D + skb);
            int byte = (se << 8) + (skb << 1);
            byte ^= (se & 7) << 4;
            *(bfrag8*)((char*)at + byte) = v;
        }
        __syncthreads();

        facc4 acc0 = {0.f, 0.f, 0.f, 0.f}, acc1 = {0.f, 0.f, 0.f, 0.f};
        int eb = (mtile << 4) + (lane & 15);
        int c0 = colbase + (lane & 15);
        int c1 = c0 + 16;
#pragma unroll
        for (int kk = 0; kk < 4; ++kk) {
            int kbase = (kk << 5) + ((lane >> 4) << 3);
            int ab = ((eb << 8) + (kbase << 1)) ^ ((eb & 7) << 4);
            bfrag8 a = *(const bfrag8*)((char*)at + ab);
            int b0 = ((c0 << 8) + (kbase << 1)) ^ ((c0 & 7) << 4);
            bfrag8 bv0 = *(const bfrag8*)((char*)wt + b0);
            int b1 = ((c1 << 8) + (kbase << 1)) ^ ((c1 & 7) << 4);
            bfrag8 bv1 = *(const bfrag8*)((char*)wt + b1);
            acc0 = __builtin_amdgcn_mfma_f32_16x16x32_bf16(a, bv0, acc0, 0, 0, 0);
            acc1 = __builtin_amdgcn_mfma_f32_16x16x32_bf16(a, bv1, acc1, 0, 0, 0);
        }
        // store: C/D mapping col=lane&15, row=(lane>>4)*4+reg
        int ebase = (mtile << 4) + ((lane >> 4) << 2);
#pragma unroll
        for (int j = 0; j < 4; ++j) {
            int p = epos[ebase + j];
            if (p >= 0) {
                unsigned short* q = srcs16 + (size_t)p * D + c0;
                q[0]  = f2bf(alpha * acc0[j]);
                q[16] = f2bf(alpha * acc1[j]);
            }
        }
    }
}

// ---------------- phase 2: out[n] = relu(indeg*(vfts@update) + sum srcs rows) ----------------
#define INIT_NODES 16
__global__ void __launch_bounds__(256)
k_final(const float* __restrict__ vfts, const float* __restrict__ update,
        const int* __restrict__ dstbase, const unsigned short* __restrict__ srcs16,
        float* __restrict__ out, int N) {
    __shared__ float upd[D * D];
    __shared__ float rows[INIT_NODES][APAD];
    int t = threadIdx.x;
    for (int idx = t; idx < D * D; idx += 256) upd[idx] = update[idx];
    int g = t >> 5;
    int cg = t & 31;
    for (int nb = blockIdx.x * INIT_NODES; nb < N; nb += gridDim.x * INIT_NODES) {
        __syncthreads();
        for (int idx = t; idx < INIT_NODES * D; idx += 256) {
            int nn = idx >> 7, k = idx & 127;
            int n = nb + nn;
            rows[nn][k] = (n < N) ? vfts[n * D + k] : 0.f;
        }
        __syncthreads();
        int n0 = g * 2, n1 = g * 2 + 1;
        float acc0[4] = {0, 0, 0, 0}, acc1[4] = {0, 0, 0, 0};
#pragma unroll 4
        for (int k = 0; k < D; ++k) {
            float4 w = *(const float4*)&upd[k * D + cg * 4];
            float a0 = rows[n0][k], a1 = rows[n1][k];
            acc0[0] += a0 * w.x; acc0[1] += a0 * w.y; acc0[2] += a0 * w.z; acc0[3] += a0 * w.w;
            acc1[0] += a1 * w.x; acc1[1] += a1 * w.y; acc1[2] += a1 * w.z; acc1[3] += a1 * w.w;
        }
        int na = nb + n0, nc = nb + n1;
        if (na < N) {
            int b0 = dstbase[na], b1 = dstbase[na + 1];
            float deg = (float)(b1 - b0);
            float r0 = deg * acc0[0], r1 = deg * acc0[1], r2 = deg * acc0[2], r3 = deg * acc0[3];
            for (int p = b0; p < b1; ++p) {
                ushort4 u = *(const ushort4*)(srcs16 + (size_t)p * D + cg * 4);
                r0 += bf2f(u.x); r1 += bf2f(u.y); r2 += bf2f(u.z); r3 += bf2f(u.w);
            }
            *(float4*)&out[(size_t)na * D + cg * 4] =
                make_float4(fmaxf(r0, 0.f), fmaxf(r1, 0.f), fmaxf(r2, 0.f), fmaxf(r3, 0.f));
        }
        if (nc < N) {
            int b0 = dstbase[nc], b1 = dstbase[nc + 1];
            float deg = (float)(b1 - b0);
            float r0 = deg * acc1[0], r1 = deg * acc1[1], r2 = deg * acc1[2], r3 = deg * acc1[3];
            for (int p = b0; p < b1; ++p) {
                ushort4 u = *(const ushort4*)(srcs16 + (size_t)p * D + cg * 4);
                r0 += bf2f(u.x); r1 += bf2f(u.y); r2 += bf2f(u.z); r3 += bf2f(u.w);
            }
            *(float4*)&out[(size_t)nc * D + cg * 4] =
                make_float4(fmaxf(r0, 0.f), fmaxf(r1, 0.f), fmaxf(r2, 0.f), fmaxf(r3, 0.f));
        }
    }
}

// ================= fallback path (atomic k_edge, used if ws too small) =================
__global__ void k_init(const float* __restrict__ vfts, const float* __restrict__ update,
                       const int* __restrict__ indeg, float* __restrict__ out, int N) {
    __shared__ float upd[D * D];
    __shared__ float rows[INIT_NODES][APAD];
    int t = threadIdx.x;
    for (int idx = t; idx < D * D; idx += 256) upd[idx] = update[idx];
    int g = t >> 5;
    int cg = t & 31;
    for (int nb = blockIdx.x * INIT_NODES; nb < N; nb += gridDim.x * INIT_NODES) {
        __syncthreads();
        for (int idx = t; idx < INIT_NODES * D; idx += 256) {
            int nn = idx >> 7, k = idx & 127;
            int n = nb + nn;
            rows[nn][k] = (n < N) ? vfts[n * D + k] : 0.f;
        }
        __syncthreads();
        int n0 = g * 2, n1 = g * 2 + 1;
        float acc0[4] = {0, 0, 0, 0}, acc1[4] = {0, 0, 0, 0};
#pragma unroll 4
        for (int k = 0; k < D; ++k) {
            float4 w = *(const float4*)&upd[k * D + cg * 4];
            float a0 = rows[n0][k], a1 = rows[n1][k];
            acc0[0] += a0 * w.x; acc0[1] += a0 * w.y; acc0[2] += a0 * w.z; acc0[3] += a0 * w.w;
            acc1[0] += a1 * w.x; acc1[1] += a1 * w.y; acc1[2] += a1 * w.z; acc1[3] += a1 * w.w;
        }
        int na = nb + n0, nc = nb + n1;
        if (na < N) {
            float deg = (float)indeg[na];
            *(float4*)&out[na * D + cg * 4] =
                make_float4(deg * acc0[0], deg * acc0[1], deg * acc0[2], deg * acc0[3]);
        }
        if (nc < N) {
            float deg = (float)indeg[nc];
            *(float4*)&out[nc * D + cg * 4] =
                make_float4(deg * acc1[0], deg * acc1[1], deg * acc1[2], deg * acc1[3]);
        }
    }
}

__global__ void __launch_bounds__(512)
k_edge_at(const float* __restrict__ vfts, const int* __restrict__ adjs,
          const float* __restrict__ wrel, const float* __restrict__ alphas,
          const int* __restrict__ basep, const int* __restrict__ sorted,
          float* __restrict__ out, int E) {
    __shared__ unsigned short wt[D * D];
    __shared__ unsigned short at[EPB * D];
    __shared__ int esrc[EPB], edst[EPB];
    int t = threadIdx.x;
    int r = blockIdx.x / PPART;
    int bp = blockIdx.x % PPART;
    const float* wr = wrel + r * D * D;
    for (int i = t; i < D * D; i += 512) {
        int k = i >> 7, col = i & 127;
        int byte = (col << 8) + (k << 1);
        byte ^= (col & 7) << 4;
        *(unsigned short*)((char*)wt + byte) = f2bf(wr[i]);
    }
    float alpha = alphas[r];
    int s0 = basep[r], s1 = basep[r + 1];
    int lane = t & 63;
    int wave = t >> 6;
    int mtile = wave >> 2;
    int colbase = (wave & 3) << 5;
    int se = t >> 4;
    int skb = (t & 15) << 3;
    for (int off = s0 + bp * EPB; off < s1; off += PPART * EPB) {
        __syncthreads();
        if (t < EPB) {
            int idx = off + t;
            if (idx < s1) {
                int eid = sorted[idx];
                esrc[t] = adjs[eid];
                edst[t] = adjs[E + eid];
            } else {
                esrc[t] = 0;
                edst[t] = -1;
            }
        }
        __syncthreads();
        {
            const float* sp = vfts + (size_t)esrc[se] * D + skb;
            float4 f0 = *(const float4*)sp;
            float4 f1 = *(const float4*)(sp + 4);
            bfrag8 v;
            v[0] = (short)f2bf(f0.x); v[1] = (short)f2bf(f0.y);
            v[2] = (short)f2bf(f0.z); v[3] = (short)f2bf(f0.w);
            v[4] = (short)f2bf(f1.x); v[5] = (short)f2bf(f1.y);
            v[6] = (short)f2bf(f1.z); v[7] = (short)f2bf(f1.w);
            int byte = (se << 8) + (skb << 1);
            byte ^= (se & 7) << 4;
            *(bfrag8*)((char*)at + byte) = v;
        }
        __syncthreads();
        facc4 acc0 = {0.f, 0.f, 0.f, 0.f}, acc1 = {0.f, 0.f, 0.f, 0.f};
        int eb = (mtile << 4) + (lane & 15);
        int c0 = colbase + (lane & 15);
        int c1 = c0 + 16;
#pragma unroll
        for (int kk = 0; kk < 4; ++kk) {
            int kbase = (kk << 5) + ((lane >> 4) << 3);
            int ab = ((eb << 8) + (kbase << 1)) ^ ((eb & 7) << 4);
            bfrag8 a = *(const bfrag8*)((char*)at + ab);
            int b0 = ((c0 << 8) + (kbase << 1)) ^ ((c0 & 7) << 4);
            bfrag8 bv0 = *(const bfrag8*)((char*)wt + b0);
            int b1 = ((c1 << 8) + (kbase << 1)) ^ ((c1 & 7) << 4);
            bfrag8 bv1 = *(const bfrag8*)((char*)wt + b1);
            acc0 = __builtin_amdgcn_mfma_f32_16x16x32_bf16(a, bv0, acc0, 0, 0, 0);
            acc1 = __builtin_amdgcn_mfma_f32_16x16x32_bf16(a, bv1, acc1, 0, 0, 0);
        }
        int ebase = (mtile << 4) + ((lane >> 4) << 2);
#pragma unroll
        for (int j = 0; j < 4; ++j) {
            int d = edst[ebase + j];
            if (d >= 0) {
                float* p = out + (size_t)d * D + c0;
                atomicAdd(p, alpha * acc0[j]);
                atomicAdd(p + 16, alpha * acc1[j]);
            }
        }
    }
}

__global__ void k_relu(float* __restrict__ out, int total4) {
    int i = blockIdx.x * blockDim.x + threadIdx.x;
    int stride = gridDim.x * blockDim.x;
    for (; i < total4; i += stride) {
        float4 v = ((float4*)out)[i];
        v.x = fmaxf(v.x, 0.f);
        v.y = fmaxf(v.y, 0.f);
        v.z = fmaxf(v.z, 0.f);
        v.w = fmaxf(v.w, 0.f);
        ((float4*)out)[i] = v;
    }
}

extern "C" void kernel_launch(void* const* d_in, const int* in_sizes, int n_in,
                              void* d_out, int out_size, void* d_ws, size_t ws_size,
                              hipStream_t stream) {
    const float* vfts   = (const float*)d_in[0];
    const int*   adjs   = (const int*)d_in[1];
    const int*   rels   = (const int*)d_in[2];
    const float* er     = (const float*)d_in[3];
    const float* ert    = (const float*)d_in[4];
    const float* weight = (const float*)d_in[5];
    const float* comp   = (const float*)d_in[6];
    const float* w1     = (const float*)d_in[7];
    const float* b1     = (const float*)d_in[8];
    const float* w2     = (const float*)d_in[9];
    const float* b2     = (const float*)d_in[10];
    const float* update = (const float*)d_in[11];
    float* out = (float*)d_out;

    int N = in_sizes[0] / D;
    int E = in_sizes[2];
    int Nr = (N + 63) & ~63;

    char* ws = (char*)d_ws;
    // --- new-path layout ---
    size_t o = 0;
    float* wrel = (float*)(ws + o);            o += (size_t)RNUM * D * D * 4;          // 1 MB
    float* alphas = (float*)(ws + o);          o += 256;
    unsigned short* vb = (unsigned short*)(ws + o);     o += (size_t)N * D * 2;        // 12.8 MB
    o = (o + 255) & ~(size_t)255;
    unsigned short* srcs16 = (unsigned short*)(ws + o); o += (size_t)E * D * 2;        // 102.4 MB
    o = (o + 255) & ~(size_t)255;
    int* basep     = (int*)(ws + o);           o += 128;
    int* indeg     = (int*)(ws + o);           o += (size_t)Nr * 4;
    int* blockHist = (int*)(ws + o);           o += (size_t)NBLK * RNUM * 4;
    int* blockBase = (int*)(ws + o);           o += (size_t)NBLK * RNUM * 4;
    int* sorted    = (int*)(ws + o);           o += (size_t)E * 4;
    int* chunkSum  = (int*)(ws + o);           o += NBLK * 4;
    int* chunkBase = (int*)(ws + o);           o += NBLK * 4;
    int* dstbase   = (int*)(ws + o);           o += (size_t)(Nr + 64) * 4;
    int* dpos      = (int*)(ws + o);           o += (size_t)Nr * 4;
    int* possorted = (int*)(ws + o);           o += (size_t)E * 4;
    bool big = (o <= ws_size);

    if (big) {
        hipMemsetAsync(indeg, 0, (size_t)Nr * 4, stream);
        k_wrel<<<256, 256, 0, stream>>>(comp, weight, wrel);
        k_alphas<<<RNUM, D, 0, stream>>>(vfts, adjs, er, ert, w1, b1, w2, b2, alphas, E);
        k_prep<<<1024, 256, 0, stream>>>(vfts, vb, N * D / 8);
        k_hist<<<NBLK, 256, 0, stream>>>(adjs, rels, E, blockHist, indeg);
        k_prefix2<<<1, 256, 0, stream>>>(blockHist, basep, blockBase);
        k_scatter2<<<NBLK, 256, 0, stream>>>(rels, E, blockBase, sorted);
        k_scanA<<<NBLK, 256, 0, stream>>>(indeg, N, chunkSum);
        k_scanB<<<1, 64, 0, stream>>>(chunkSum, chunkBase, dstbase, N);
        k_scanC<<<NBLK, 256, 0, stream>>>(indeg, N, chunkBase, dstbase, dpos);
        k_dstpos<<<256, 256, 0, stream>>>(adjs, sorted, E, dpos, possorted);
        k_edge<<<RNUM * PPART, 512, 0, stream>>>(vb, adjs, wrel, alphas, basep, sorted,
                                                 possorted, srcs16, E);
        k_final<<<512, 256, 0, stream>>>(vfts, update, dstbase, srcs16, out, N);
    } else {
        // fallback: round-5 passing layout (atomic scatter)
        float* fwrel   = (float*)ws;
        float* falphas = (float*)(ws + (1 << 20));
        int* ib = (int*)(ws + (1 << 20) + 256);
        int* fbasep     = ib;
        int* findeg     = ib + 32;
        int* fblockHist = findeg + Nr;
        int* fblockBase = fblockHist + NBLK * RNUM;
        int* fsorted    = fblockBase + NBLK * RNUM;

        hipMemsetAsync(findeg, 0, (size_t)Nr * 4, stream);
        k_wrel<<<256, 256, 0, stream>>>(comp, weight, fwrel);
        k_alphas<<<RNUM, D, 0, stream>>>(vfts, adjs, er, ert, w1, b1, w2, b2, falphas, E);
        k_hist<<<NBLK, 256, 0, stream>>>(adjs, rels, E, fblockHist, findeg);
        k_prefix2<<<1, 256, 0, stream>>>(fblockHist, fbasep, fblockBase);
        k_scatter2<<<NBLK, 256, 0, stream>>>(rels, E, fblockBase, fsorted);
        k_init<<<512, 256, 0, stream>>>(vfts, update, findeg, out, N);
        k_edge_at<<<RNUM * PPART, 512, 0, stream>>>(vfts, adjs, fwrel, falphas, fbasep,
                                                    fsorted, out, E);
        k_relu<<<512, 256, 0, stream>>>(out, N * D / 4);
    }
}

// Round 7
// 321.417 us; speedup vs baseline: 9.9879x; 1.1814x over previous
//
#include <hip/hip_runtime.h>
#include <hip/hip_bf16.h>

#define D 128
#define DE 32
#define RNUM 16
#define BNUM 8
#define APAD 132
#define EPB 32       // edges per k_edge tile
#define NBLK 256     // blocks for hist/scatter/scan passes
#define PPART 32     // partitions per relation in k_edge

typedef __attribute__((ext_vector_type(8))) short bfrag8;   // 8 bf16 in 4 VGPRs
typedef __attribute__((ext_vector_type(4))) float facc4;

__device__ inline unsigned short f2bf(float f) {
    union { float f; unsigned int u; } v; v.f = f;
    unsigned int u = v.u + 0x7FFFu + ((v.u >> 16) & 1u);   // RNE
    return (unsigned short)(u >> 16);
}
__device__ inline float bf2f(unsigned short h) {
    union { unsigned int u; float f; } v; v.u = ((unsigned int)h) << 16; return v.f;
}

// ---------------- w_rel[r] = sum_b comp[r,b] * weight[b] ----------------
__global__ void k_wrel(const float* __restrict__ comp, const float* __restrict__ weight,
                       float* __restrict__ wrel) {
    int idx = blockIdx.x * blockDim.x + threadIdx.x;
    int total = RNUM * D * D;
    int stride = gridDim.x * blockDim.x;
    for (; idx < total; idx += stride) {
        int r = idx >> 14;
        int rest = idx & 16383;
        float s = 0.f;
#pragma unroll
        for (int b = 0; b < BNUM; ++b) s += comp[r * BNUM + b] * weight[b * 16384 + rest];
        wrel[idx] = s;
    }
}

// ---------------- attention alphas for edges 0..15 only ----------------
__global__ void k_alphas(const float* __restrict__ vfts, const int* __restrict__ adjs,
                         const float* __restrict__ er, const float* __restrict__ ert,
                         const float* __restrict__ w1, const float* __restrict__ b1,
                         const float* __restrict__ w2, const float* __restrict__ b2,
                         float* __restrict__ alphas, int E) {
    __shared__ float erps[2 * D + 2 * DE];
    __shared__ float red[D];
    int e = blockIdx.x, t = threadIdx.x;
    int src = adjs[e], dst = adjs[E + e];
    erps[t] = vfts[src * D + t];
    erps[D + t] = vfts[dst * D + t];
    if (t < DE) {
        erps[2 * D + t] = er[e * DE + t];
        erps[2 * D + DE + t] = ert[e * DE + t];
    }
    __syncthreads();
    float h = b1[t];
    for (int k = 0; k < 2 * D + 2 * DE; ++k) h += erps[k] * w1[k * D + t];
    h = fmaxf(h, 0.f);
    red[t] = h * w2[t];
    __syncthreads();
    for (int s = 64; s > 0; s >>= 1) {
        if (t < s) red[t] += red[t + s];
        __syncthreads();
    }
    if (t == 0) alphas[e] = 1.f / (1.f + expf(-(red[0] + b2[0])));
}

// ---------------- vfts -> bf16 copy ----------------
__global__ void k_prep(const float* __restrict__ vfts, unsigned short* __restrict__ vb,
                       int total8) {
    int i = blockIdx.x * blockDim.x + threadIdx.x;
    int stride = gridDim.x * blockDim.x;
    for (; i < total8; i += stride) {
        float4 f0 = ((const float4*)vfts)[i * 2];
        float4 f1 = ((const float4*)vfts)[i * 2 + 1];
        bfrag8 v;
        v[0] = (short)f2bf(f0.x); v[1] = (short)f2bf(f0.y);
        v[2] = (short)f2bf(f0.z); v[3] = (short)f2bf(f0.w);
        v[4] = (short)f2bf(f1.x); v[5] = (short)f2bf(f1.y);
        v[6] = (short)f2bf(f1.z); v[7] = (short)f2bf(f1.w);
        ((bfrag8*)vb)[i] = v;
    }
}

// ---------------- pass A: per-block relation histogram + node in-degree ----------------
__global__ void k_hist(const int* __restrict__ adjs, const int* __restrict__ rels, int E,
                       int* __restrict__ blockHist, int* __restrict__ indeg) {
    __shared__ int h[4][RNUM];
    int t = threadIdx.x;
    if (t < 4 * RNUM) ((int*)h)[t] = 0;
    __syncthreads();
    int w = t >> 6;
    int chunk = (E + NBLK - 1) / NBLK;
    int start = blockIdx.x * chunk;
    int end = min(start + chunk, E);
    for (int i = start + t; i < end; i += 256) {
        atomicAdd(&h[w][rels[i]], 1);
        atomicAdd(&indeg[adjs[E + i]], 1);
    }
    __syncthreads();
    if (t < RNUM)
        blockHist[blockIdx.x * RNUM + t] = h[0][t] + h[1][t] + h[2][t] + h[3][t];
}

// ---------------- pass B: prefix sums -> basep[17], blockBase[NBLK][16] ----------------
__global__ void k_prefix2(const int* __restrict__ blockHist, int* __restrict__ basep,
                          int* __restrict__ blockBase) {
    __shared__ int hist[NBLK * RNUM];
    __shared__ int pre[NBLK * RNUM];
    __shared__ int bp[RNUM + 1];
    int t = threadIdx.x;
    for (int i = t; i < NBLK * RNUM; i += 256) hist[i] = blockHist[i];
    __syncthreads();
    if (t < RNUM) {
        int s = 0;
        for (int b = 0; b < NBLK; ++b) {
            pre[b * RNUM + t] = s;
            s += hist[b * RNUM + t];
        }
        bp[t] = s;
    }
    __syncthreads();
    if (t == 0) {
        int s = 0;
        for (int r = 0; r < RNUM; ++r) {
            int c = bp[r];
            bp[r] = s;
            basep[r] = s;
            s += c;
        }
        bp[RNUM] = s;
        basep[RNUM] = s;
    }
    __syncthreads();
    for (int i = t; i < NBLK * RNUM; i += 256)
        blockBase[i] = pre[i] + bp[i & (RNUM - 1)];
}

// ---------------- pass C: scatter edge ids into relation-sorted order ----------------
__global__ void k_scatter2(const int* __restrict__ rels, int E,
                           const int* __restrict__ blockBase, int* __restrict__ sorted) {
    __shared__ int pos[RNUM];
    int t = threadIdx.x;
    if (t < RNUM) pos[t] = blockBase[blockIdx.x * RNUM + t];
    __syncthreads();
    int chunk = (E + NBLK - 1) / NBLK;
    int start = blockIdx.x * chunk;
    int end = min(start + chunk, E);
    for (int i = start + t; i < end; i += 256) {
        int p = atomicAdd(&pos[rels[i]], 1);
        sorted[p] = i;
    }
}

// ---------------- indeg prefix scan (3 passes) -> dstbase[N+1], dpos ----------------
__global__ void k_scanA(const int* __restrict__ indeg, int N, int* __restrict__ chunkSum) {
    __shared__ int sc[256];
    int t = threadIdx.x;
    int chunk = (N + NBLK - 1) / NBLK;
    int n0 = blockIdx.x * chunk;
    int v = (t < chunk && n0 + t < N) ? indeg[n0 + t] : 0;
    sc[t] = v;
    __syncthreads();
    for (int s = 128; s > 0; s >>= 1) {
        if (t < s) sc[t] += sc[t + s];
        __syncthreads();
    }
    if (t == 0) chunkSum[blockIdx.x] = sc[0];
}

__global__ void k_scanB(const int* __restrict__ chunkSum, int* __restrict__ chunkBase,
                        int* __restrict__ dstbase, int N) {
    if (threadIdx.x == 0) {
        int s = 0;
        for (int b = 0; b < NBLK; ++b) {
            chunkBase[b] = s;
            s += chunkSum[b];
        }
        dstbase[N] = s;
    }
}

__global__ void k_scanC(const int* __restrict__ indeg, int N,
                        const int* __restrict__ chunkBase, int* __restrict__ dstbase,
                        int* __restrict__ dpos) {
    __shared__ int sc[256];
    int t = threadIdx.x;
    int chunk = (N + NBLK - 1) / NBLK;
    int n0 = blockIdx.x * chunk;
    bool valid = (t < chunk) && (n0 + t < N);
    int v = valid ? indeg[n0 + t] : 0;
    sc[t] = v;
    __syncthreads();
    for (int ofs = 1; ofs < 256; ofs <<= 1) {
        int x = (t >= ofs) ? sc[t - ofs] : 0;
        __syncthreads();
        sc[t] += x;
        __syncthreads();
    }
    if (valid) {
        int excl = chunkBase[blockIdx.x] + sc[t] - v;
        dstbase[n0 + t] = excl;
        dpos[n0 + t] = excl;
    }
}

// ---------------- dst-sorted position for each rel-sorted slot ----------------
__global__ void k_dstpos(const int* __restrict__ adjs, const int* __restrict__ sorted, int E,
                         int* __restrict__ dpos, int* __restrict__ possorted) {
    int i = blockIdx.x * blockDim.x + threadIdx.x;
    int stride = gridDim.x * blockDim.x;
    for (; i < E; i += stride) {
        int eid = sorted[i];
        int dst = adjs[E + eid];
        possorted[i] = atomicAdd(&dpos[dst], 1);
    }
}

// ---------------- phase 1: per-relation MFMA edge GEMM -> srcs16 (no atomics) ----------------
__global__ void __launch_bounds__(512)
k_edge(const unsigned short* __restrict__ vb, const int* __restrict__ adjs,
       const float* __restrict__ wrel, const float* __restrict__ alphas,
       const int* __restrict__ basep, const int* __restrict__ sorted,
       const int* __restrict__ possorted, unsigned short* __restrict__ srcs16, int E) {
    __shared__ unsigned short wt[D * D];      // 32 KB
    __shared__ unsigned short at[EPB * D];    // 8 KB
    __shared__ int esrc[EPB], epos[EPB];
    int t = threadIdx.x;
    int r = blockIdx.x / PPART;
    int bp = blockIdx.x % PPART;

    // stage W_r^T: wt[col][k] = wrel[r][k][col], bf16, byte ^= (col&7)<<4
    const float* wr = wrel + r * D * D;
    for (int i = t; i < D * D; i += 512) {
        int k = i >> 7, col = i & 127;
        int byte = (col << 8) + (k << 1);
        byte ^= (col & 7) << 4;
        *(unsigned short*)((char*)wt + byte) = f2bf(wr[i]);
    }
    float alpha = alphas[r];
    int s0 = basep[r], s1 = basep[r + 1];

    int lane = t & 63;
    int wave = t >> 6;
    int mtile = wave >> 2;            // 0..1
    int colbase = (wave & 3) << 5;    // 0,32,64,96
    int se = t >> 4;                  // staging: edge 0..31
    int skb = (t & 15) << 3;          // staging: k-base 0..120

    for (int off = s0 + bp * EPB; off < s1; off += PPART * EPB) {
        __syncthreads();
        if (t < EPB) {
            int idx = off + t;
            if (idx < s1) {
                int eid = sorted[idx];
                esrc[t] = adjs[eid];
                epos[t] = possorted[idx];
            } else {
                esrc[t] = 0;
                epos[t] = -1;
            }
        }
        __syncthreads();
        // stage A: 8 bf16 per thread -> one swizzled 16B LDS write
        {
            bfrag8 v = *(const bfrag8*)(vb + (size_t)esrc[se] * D + skb);
            int byte = (se << 8) + (skb << 1);
            byte ^= (se & 7) << 4;
            *(bfrag8*)((char*)at + byte) = v;
        }
        __syncthreads();

        facc4 acc0 = {0.f, 0.f, 0.f, 0.f}, acc1 = {0.f, 0.f, 0.f, 0.f};
        int eb = (mtile << 4) + (lane & 15);
        int c0 = colbase + (lane & 15);
        int c1 = c0 + 16;
#pragma unroll
        for (int kk = 0; kk < 4; ++kk) {
            int kbase = (kk << 5) + ((lane >> 4) << 3);
            int ab = ((eb << 8) + (kbase << 1)) ^ ((eb & 7) << 4);
            bfrag8 a = *(const bfrag8*)((char*)at + ab);
            int b0 = ((c0 << 8) + (kbase << 1)) ^ ((c0 & 7) << 4);
            bfrag8 bv0 = *(const bfrag8*)((char*)wt + b0);
            int b1 = ((c1 << 8) + (kbase << 1)) ^ ((c1 & 7) << 4);
            bfrag8 bv1 = *(const bfrag8*)((char*)wt + b1);
            acc0 = __builtin_amdgcn_mfma_f32_16x16x32_bf16(a, bv0, acc0, 0, 0, 0);
            acc1 = __builtin_amdgcn_mfma_f32_16x16x32_bf16(a, bv1, acc1, 0, 0, 0);
        }
        // store: C/D mapping col=lane&15, row=(lane>>4)*4+reg
        int ebase = (mtile << 4) + ((lane >> 4) << 2);
#pragma unroll
        for (int j = 0; j < 4; ++j) {
            int p = epos[ebase + j];
            if (p >= 0) {
                unsigned short* q = srcs16 + (size_t)p * D + c0;
                q[0]  = f2bf(alpha * acc0[j]);
                q[16] = f2bf(alpha * acc1[j]);
            }
        }
    }
}

// ---------------- phase 2a: raw dsts = vfts @ update -> out (MFMA, contiguous) ----------------
__global__ void __launch_bounds__(512)
k_dsts(const unsigned short* __restrict__ vb, const float* __restrict__ update,
       float* __restrict__ out, int N) {
    __shared__ unsigned short wt[D * D];      // 32 KB: update^T bf16, swizzled
    __shared__ unsigned short at[32 * D];     // 8 KB: 32 node rows
    int t = threadIdx.x;
    for (int i = t; i < D * D; i += 512) {
        int k = i >> 7, col = i & 127;
        int byte = (col << 8) + (k << 1);
        byte ^= (col & 7) << 4;
        *(unsigned short*)((char*)wt + byte) = f2bf(update[i]);
    }
    int lane = t & 63;
    int wave = t >> 6;
    int mtile = wave >> 2;            // 0..1
    int colbase = (wave & 3) << 5;    // 0,32,64,96
    int se = t >> 4;                  // node 0..31 within tile
    int skb = (t & 15) << 3;          // k-base
    int nb = blockIdx.x * 32;
    {
        int n = nb + se;
        if (n >= N) n = N - 1;
        bfrag8 v = *(const bfrag8*)(vb + (size_t)n * D + skb);
        int byte = ((se << 8) + (skb << 1)) ^ ((se & 7) << 4);
        *(bfrag8*)((char*)at + byte) = v;
    }
    __syncthreads();
    facc4 acc0 = {0.f, 0.f, 0.f, 0.f}, acc1 = {0.f, 0.f, 0.f, 0.f};
    int eb = (mtile << 4) + (lane & 15);
    int c0 = colbase + (lane & 15);
    int c1 = c0 + 16;
#pragma unroll
    for (int kk = 0; kk < 4; ++kk) {
        int kbase = (kk << 5) + ((lane >> 4) << 3);
        int ab = ((eb << 8) + (kbase << 1)) ^ ((eb & 7) << 4);
        bfrag8 a = *(const bfrag8*)((char*)at + ab);
        int b0 = ((c0 << 8) + (kbase << 1)) ^ ((c0 & 7) << 4);
        bfrag8 bv0 = *(const bfrag8*)((char*)wt + b0);
        int b1 = ((c1 << 8) + (kbase << 1)) ^ ((c1 & 7) << 4);
        bfrag8 bv1 = *(const bfrag8*)((char*)wt + b1);
        acc0 = __builtin_amdgcn_mfma_f32_16x16x32_bf16(a, bv0, acc0, 0, 0, 0);
        acc1 = __builtin_amdgcn_mfma_f32_16x16x32_bf16(a, bv1, acc1, 0, 0, 0);
    }
    int ebase = (mtile << 4) + ((lane >> 4) << 2);
#pragma unroll
    for (int j = 0; j < 4; ++j) {
        int n = nb + ebase + j;
        if (n < N) {
            float* q = out + (size_t)n * D + c0;
            q[0]  = acc0[j];
            q[16] = acc1[j];
        }
    }
}

// ---------------- phase 2b: out[n] = relu(deg*out[n] + sum srcs rows) ----------------
// one wave per node; lane l owns columns 2l, 2l+1. No LDS -> high occupancy.
__global__ void __launch_bounds__(256)
k_sum(const int* __restrict__ dstbase, const unsigned short* __restrict__ srcs16,
      float* __restrict__ out, int N) {
    int wid = (blockIdx.x * 256 + threadIdx.x) >> 6;   // node id
    int lane = threadIdx.x & 63;
    if (wid >= N) return;
    int b0 = dstbase[wid], b1 = dstbase[wid + 1];
    float deg = (float)(b1 - b0);
    const unsigned int* base = (const unsigned int*)srcs16;
    float a0 = 0.f, a1 = 0.f;
    int p = b0;
    for (; p + 4 <= b1; p += 4) {
        unsigned int u0 = base[(size_t)(p + 0) * 64 + lane];
        unsigned int u1 = base[(size_t)(p + 1) * 64 + lane];
        unsigned int u2 = base[(size_t)(p + 2) * 64 + lane];
        unsigned int u3 = base[(size_t)(p + 3) * 64 + lane];
        a0 += bf2f((unsigned short)u0) + bf2f((unsigned short)u1) +
              bf2f((unsigned short)u2) + bf2f((unsigned short)u3);
        a1 += bf2f((unsigned short)(u0 >> 16)) + bf2f((unsigned short)(u1 >> 16)) +
              bf2f((unsigned short)(u2 >> 16)) + bf2f((unsigned short)(u3 >> 16));
    }
    for (; p < b1; ++p) {
        unsigned int u = base[(size_t)p * 64 + lane];
        a0 += bf2f((unsigned short)u);
        a1 += bf2f((unsigned short)(u >> 16));
    }
    float2* op = (float2*)out + (size_t)wid * 64 + lane;
    float2 d = *op;
    *op = make_float2(fmaxf(deg * d.x + a0, 0.f), fmaxf(deg * d.y + a1, 0.f));
}

// ================= fallback path (atomic k_edge, used if ws too small) =================
#define INIT_NODES 16
__global__ void k_init(const float* __restrict__ vfts, const float* __restrict__ update,
                       const int* __restrict__ indeg, float* __restrict__ out, int N) {
    __shared__ float upd[D * D];
    __shared__ float rows[INIT_NODES][APAD];
    int t = threadIdx.x;
    for (int idx = t; idx < D * D; idx += 256) upd[idx] = update[idx];
    int g = t >> 5;
    int cg = t & 31;
    for (int nb = blockIdx.x * INIT_NODES; nb < N; nb += gridDim.x * INIT_NODES) {
        __syncthreads();
        for (int idx = t; idx < INIT_NODES * D; idx += 256) {
            int nn = idx >> 7, k = idx & 127;
            int n = nb + nn;
            rows[nn][k] = (n < N) ? vfts[n * D + k] : 0.f;
        }
        __syncthreads();
        int n0 = g * 2, n1 = g * 2 + 1;
        float acc0[4] = {0, 0, 0, 0}, acc1[4] = {0, 0, 0, 0};
#pragma unroll 4
        for (int k = 0; k < D; ++k) {
            float4 w = *(const float4*)&upd[k * D + cg * 4];
            float a0 = rows[n0][k], a1 = rows[n1][k];
            acc0[0] += a0 * w.x; acc0[1] += a0 * w.y; acc0[2] += a0 * w.z; acc0[3] += a0 * w.w;
            acc1[0] += a1 * w.x; acc1[1] += a1 * w.y; acc1[2] += a1 * w.z; acc1[3] += a1 * w.w;
        }
        int na = nb + n0, nc = nb + n1;
        if (na < N) {
            float deg = (float)indeg[na];
            *(float4*)&out[na * D + cg * 4] =
                make_float4(deg * acc0[0], deg * acc0[1], deg * acc0[2], deg * acc0[3]);
        }
        if (nc < N) {
            float deg = (float)indeg[nc];
            *(float4*)&out[nc * D + cg * 4] =
                make_float4(deg * acc1[0], deg * acc1[1], deg * acc1[2], deg * acc1[3]);
        }
    }
}

__global__ void __launch_bounds__(512)
k_edge_at(const float* __restrict__ vfts, const int* __restrict__ adjs,
          const float* __restrict__ wrel, const float* __restrict__ alphas,
          const int* __restrict__ basep, const int* __restrict__ sorted,
          float* __restrict__ out, int E) {
    __shared__ unsigned short wt[D * D];
    __shared__ unsigned short at[EPB * D];
    __shared__ int esrc[EPB], edst[EPB];
    int t = threadIdx.x;
    int r = blockIdx.x / PPART;
    int bp = blockIdx.x % PPART;
    const float* wr = wrel + r * D * D;
    for (int i = t; i < D * D; i += 512) {
        int k = i >> 7, col = i & 127;
        int byte = (col << 8) + (k << 1);
        byte ^= (col & 7) << 4;
        *(unsigned short*)((char*)wt + byte) = f2bf(wr[i]);
    }
    float alpha = alphas[r];
    int s0 = basep[r], s1 = basep[r + 1];
    int lane = t & 63;
    int wave = t >> 6;
    int mtile = wave >> 2;
    int colbase = (wave & 3) << 5;
    int se = t >> 4;
    int skb = (t & 15) << 3;
    for (int off = s0 + bp * EPB; off < s1; off += PPART * EPB) {
        __syncthreads();
        if (t < EPB) {
            int idx = off + t;
            if (idx < s1) {
                int eid = sorted[idx];
                esrc[t] = adjs[eid];
                edst[t] = adjs[E + eid];
            } else {
                esrc[t] = 0;
                edst[t] = -1;
            }
        }
        __syncthreads();
        {
            const float* sp = vfts + (size_t)esrc[se] * D + skb;
            float4 f0 = *(const float4*)sp;
            float4 f1 = *(const float4*)(sp + 4);
            bfrag8 v;
            v[0] = (short)f2bf(f0.x); v[1] = (short)f2bf(f0.y);
            v[2] = (short)f2bf(f0.z); v[3] = (short)f2bf(f0.w);
            v[4] = (short)f2bf(f1.x); v[5] = (short)f2bf(f1.y);
            v[6] = (short)f2bf(f1.z); v[7] = (short)f2bf(f1.w);
            int byte = (se << 8) + (skb << 1);
            byte ^= (se & 7) << 4;
            *(bfrag8*)((char*)at + byte) = v;
        }
        __syncthreads();
        facc4 acc0 = {0.f, 0.f, 0.f, 0.f}, acc1 = {0.f, 0.f, 0.f, 0.f};
        int eb = (mtile << 4) + (lane & 15);
        int c0 = colbase + (lane & 15);
        int c1 = c0 + 16;
#pragma unroll
        for (int kk = 0; kk < 4; ++kk) {
            int kbase = (kk << 5) + ((lane >> 4) << 3);
            int ab = ((eb << 8) + (kbase << 1)) ^ ((eb & 7) << 4);
            bfrag8 a = *(const bfrag8*)((char*)at + ab);
            int b0 = ((c0 << 8) + (kbase << 1)) ^ ((c0 & 7) << 4);
            bfrag8 bv0 = *(const bfrag8*)((char*)wt + b0);
            int b1 = ((c1 << 8) + (kbase << 1)) ^ ((c1 & 7) << 4);
            bfrag8 bv1 = *(const bfrag8*)((char*)wt + b1);
            acc0 = __builtin_amdgcn_mfma_f32_16x16x32_bf16(a, bv0, acc0, 0, 0, 0);
            acc1 = __builtin_amdgcn_mfma_f32_16x16x32_bf16(a, bv1, acc1, 0, 0, 0);
        }
        int ebase = (mtile << 4) + ((lane >> 4) << 2);
#pragma unroll
        for (int j = 0; j < 4; ++j) {
            int d = edst[ebase + j];
            if (d >= 0) {
                float* p = out + (size_t)d * D + c0;
                atomicAdd(p, alpha * acc0[j]);
                atomicAdd(p + 16, alpha * acc1[j]);
            }
        }
    }
}

__global__ void k_relu(float* __restrict__ out, int total4) {
    int i = blockIdx.x * blockDim.x + threadIdx.x;
    int stride = gridDim.x * blockDim.x;
    for (; i < total4; i += stride) {
        float4 v = ((float4*)out)[i];
        v.x = fmaxf(v.x, 0.f);
        v.y = fmaxf(v.y, 0.f);
        v.z = fmaxf(v.z, 0.f);
        v.w = fmaxf(v.w, 0.f);
        ((float4*)out)[i] = v;
    }
}

extern "C" void kernel_launch(void* const* d_in, const int* in_sizes, int n_in,
                              void* d_out, int out_size, void* d_ws, size_t ws_size,
                              hipStream_t stream) {
    const float* vfts   = (const float*)d_in[0];
    const int*   adjs   = (const int*)d_in[1];
    const int*   rels   = (const int*)d_in[2];
    const float* er     = (const float*)d_in[3];
    const float* ert    = (const float*)d_in[4];
    const float* weight = (const float*)d_in[5];
    const float* comp   = (const float*)d_in[6];
    const float* w1     = (const float*)d_in[7];
    const float* b1     = (const float*)d_in[8];
    const float* w2     = (const float*)d_in[9];
    const float* b2     = (const float*)d_in[10];
    const float* update = (const float*)d_in[11];
    float* out = (float*)d_out;

    int N = in_sizes[0] / D;
    int E = in_sizes[2];
    int Nr = (N + 63) & ~63;

    char* ws = (char*)d_ws;
    // --- new-path layout ---
    size_t o = 0;
    float* wrel = (float*)(ws + o);            o += (size_t)RNUM * D * D * 4;          // 1 MB
    float* alphas = (float*)(ws + o);          o += 256;
    unsigned short* vb = (unsigned short*)(ws + o);     o += (size_t)N * D * 2;        // 12.8 MB
    o = (o + 255) & ~(size_t)255;
    unsigned short* srcs16 = (unsigned short*)(ws + o); o += (size_t)E * D * 2;        // 102.4 MB
    o = (o + 255) & ~(size_t)255;
    int* basep     = (int*)(ws + o);           o += 128;
    int* indeg     = (int*)(ws + o);           o += (size_t)Nr * 4;
    int* blockHist = (int*)(ws + o);           o += (size_t)NBLK * RNUM * 4;
    int* blockBase = (int*)(ws + o);           o += (size_t)NBLK * RNUM * 4;
    int* sorted    = (int*)(ws + o);           o += (size_t)E * 4;
    int* chunkSum  = (int*)(ws + o);           o += NBLK * 4;
    int* chunkBase = (int*)(ws + o);           o += NBLK * 4;
    int* dstbase   = (int*)(ws + o);           o += (size_t)(Nr + 64) * 4;
    int* dpos      = (int*)(ws + o);           o += (size_t)Nr * 4;
    int* possorted = (int*)(ws + o);           o += (size_t)E * 4;
    bool big = (o <= ws_size);

    if (big) {
        hipMemsetAsync(indeg, 0, (size_t)Nr * 4, stream);
        k_wrel<<<256, 256, 0, stream>>>(comp, weight, wrel);
        k_alphas<<<RNUM, D, 0, stream>>>(vfts, adjs, er, ert, w1, b1, w2, b2, alphas, E);
        k_prep<<<1024, 256, 0, stream>>>(vfts, vb, N * D / 8);
        k_hist<<<NBLK, 256, 0, stream>>>(adjs, rels, E, blockHist, indeg);
        k_prefix2<<<1, 256, 0, stream>>>(blockHist, basep, blockBase);
        k_scatter2<<<NBLK, 256, 0, stream>>>(rels, E, blockBase, sorted);
        k_scanA<<<NBLK, 256, 0, stream>>>(indeg, N, chunkSum);
        k_scanB<<<1, 64, 0, stream>>>(chunkSum, chunkBase, dstbase, N);
        k_scanC<<<NBLK, 256, 0, stream>>>(indeg, N, chunkBase, dstbase, dpos);
        k_dstpos<<<256, 256, 0, stream>>>(adjs, sorted, E, dpos, possorted);
        k_dsts<<<(N + 31) / 32, 512, 0, stream>>>(vb, update, out, N);
        k_edge<<<RNUM * PPART, 512, 0, stream>>>(vb, adjs, wrel, alphas, basep, sorted,
                                                 possorted, srcs16, E);
        k_sum<<<(N + 3) / 4, 256, 0, stream>>>(dstbase, srcs16, out, N);
    } else {
        // fallback: round-5 passing layout (atomic scatter)
        float* fwrel   = (float*)ws;
        float* falphas = (float*)(ws + (1 << 20));
        int* ib = (int*)(ws + (1 << 20) + 256);
        int* fbasep     = ib;
        int* findeg     = ib + 32;
        int* fblockHist = findeg + Nr;
        int* fblockBase = fblockHist + NBLK * RNUM;
        int* fsorted    = fblockBase + NBLK * RNUM;

        hipMemsetAsync(findeg, 0, (size_t)Nr * 4, stream);
        k_wrel<<<256, 256, 0, stream>>>(comp, weight, fwrel);
        k_alphas<<<RNUM, D, 0, stream>>>(vfts, adjs, er, ert, w1, b1, w2, b2, falphas, E);
        k_hist<<<NBLK, 256, 0, stream>>>(adjs, rels, E, fblockHist, findeg);
        k_prefix2<<<1, 256, 0, stream>>>(fblockHist, fbasep, fblockBase);
        k_scatter2<<<NBLK, 256, 0, stream>>>(rels, E, fblockBase, fsorted);
        k_init<<<512, 256, 0, stream>>>(vfts, update, findeg, out, N);
        k_edge_at<<<RNUM * PPART, 512, 0, stream>>>(vfts, adjs, fwrel, falphas, fbasep,
                                                    fsorted, out, E);
        k_relu<<<512, 256, 0, stream>>>(out, N * D / 4);
    }
}

// Round 8
// 304.708 us; speedup vs baseline: 10.5356x; 1.0548x over previous
//
#include <hip/hip_runtime.h>
#include <hip/hip_bf16.h>

#define D 128
#define DE 32
#define RNUM 16
#define BNUM 8
#define APAD 132
#define EPB 32
#define NBLK 256     // blocks for hist/scatter/scan passes
#define PPART 32

typedef __attribute__((ext_vector_type(8))) short bfrag8;   // 8 bf16 in 4 VGPRs
typedef __attribute__((ext_vector_type(4))) float facc4;

__device__ inline unsigned short f2bf(float f) {
    union { float f; unsigned int u; } v; v.f = f;
    unsigned int u = v.u + 0x7FFFu + ((v.u >> 16) & 1u);   // RNE
    return (unsigned short)(u >> 16);
}
__device__ inline float bf2f(unsigned short h) {
    union { unsigned int u; float f; } v; v.u = ((unsigned int)h) << 16; return v.f;
}

// ---------------- attention alphas for edges 0..15 only ----------------
__global__ void k_alphas(const float* __restrict__ vfts, const int* __restrict__ adjs,
                         const float* __restrict__ er, const float* __restrict__ ert,
                         const float* __restrict__ w1, const float* __restrict__ b1,
                         const float* __restrict__ w2, const float* __restrict__ b2,
                         float* __restrict__ alphas, int E) {
    __shared__ float erps[2 * D + 2 * DE];
    __shared__ float red[D];
    int e = blockIdx.x, t = threadIdx.x;
    int src = adjs[e], dst = adjs[E + e];
    erps[t] = vfts[src * D + t];
    erps[D + t] = vfts[dst * D + t];
    if (t < DE) {
        erps[2 * D + t] = er[e * DE + t];
        erps[2 * D + DE + t] = ert[e * DE + t];
    }
    __syncthreads();
    float h = b1[t];
    for (int k = 0; k < 2 * D + 2 * DE; ++k) h += erps[k] * w1[k * D + t];
    h = fmaxf(h, 0.f);
    red[t] = h * w2[t];
    __syncthreads();
    for (int s = 64; s > 0; s >>= 1) {
        if (t < s) red[t] += red[t + s];
        __syncthreads();
    }
    if (t == 0) alphas[e] = 1.f / (1.f + expf(-(red[0] + b2[0])));
}

// ---------------- coef[r][b] = alphas[r] * comp[r][b] ----------------
__global__ void k_coef(const float* __restrict__ alphas, const float* __restrict__ comp,
                       float* __restrict__ coef) {
    int t = threadIdx.x;
    if (t < RNUM * BNUM) coef[t] = alphas[t >> 3] * comp[t];
}

// ---------------- Wcat^T: wcatT[s][col][k] bf16; s<8 -> weight[s], s==8 -> update ----------------
__global__ void k_wcat(const float* __restrict__ weight, const float* __restrict__ update,
                       unsigned short* __restrict__ wcatT) {
    int idx = blockIdx.x * blockDim.x + threadIdx.x;
    int total = 9 * D * D;
    int stride = gridDim.x * blockDim.x;
    for (; idx < total; idx += stride) {
        int s = idx >> 14;
        int rest = idx & 16383;
        int col = rest >> 7, k = rest & 127;
        float v = (s < 8) ? weight[s * 16384 + k * D + col] : update[k * D + col];
        wcatT[idx] = f2bf(v);
    }
}

// ---------------- vfts -> bf16 copy ----------------
__global__ void k_prep(const float* __restrict__ vfts, unsigned short* __restrict__ vb,
                       int total8) {
    int i = blockIdx.x * blockDim.x + threadIdx.x;
    int stride = gridDim.x * blockDim.x;
    for (; i < total8; i += stride) {
        float4 f0 = ((const float4*)vfts)[i * 2];
        float4 f1 = ((const float4*)vfts)[i * 2 + 1];
        bfrag8 v;
        v[0] = (short)f2bf(f0.x); v[1] = (short)f2bf(f0.y);
        v[2] = (short)f2bf(f0.z); v[3] = (short)f2bf(f0.w);
        v[4] = (short)f2bf(f1.x); v[5] = (short)f2bf(f1.y);
        v[6] = (short)f2bf(f1.z); v[7] = (short)f2bf(f1.w);
        ((bfrag8*)vb)[i] = v;
    }
}

// ---------------- in-degree ----------------
__global__ void k_indeg(const int* __restrict__ adjs, int E, int* __restrict__ indeg) {
    int i = blockIdx.x * blockDim.x + threadIdx.x;
    int stride = gridDim.x * blockDim.x;
    for (; i < E; i += stride) atomicAdd(&indeg[adjs[E + i]], 1);
}

// ---------------- indeg prefix scan (3 passes) -> dstbase[N+1], dpos ----------------
__global__ void k_scanA(const int* __restrict__ indeg, int N, int* __restrict__ chunkSum) {
    __shared__ int sc[256];
    int t = threadIdx.x;
    int chunk = (N + NBLK - 1) / NBLK;
    int n0 = blockIdx.x * chunk;
    int v = (t < chunk && n0 + t < N) ? indeg[n0 + t] : 0;
    sc[t] = v;
    __syncthreads();
    for (int s = 128; s > 0; s >>= 1) {
        if (t < s) sc[t] += sc[t + s];
        __syncthreads();
    }
    if (t == 0) chunkSum[blockIdx.x] = sc[0];
}

__global__ void k_scanB(const int* __restrict__ chunkSum, int* __restrict__ chunkBase,
                        int* __restrict__ dstbase, int N) {
    if (threadIdx.x == 0) {
        int s = 0;
        for (int b = 0; b < NBLK; ++b) {
            chunkBase[b] = s;
            s += chunkSum[b];
        }
        dstbase[N] = s;
    }
}

__global__ void k_scanC(const int* __restrict__ indeg, int N,
                        const int* __restrict__ chunkBase, int* __restrict__ dstbase,
                        int* __restrict__ dpos) {
    __shared__ int sc[256];
    int t = threadIdx.x;
    int chunk = (N + NBLK - 1) / NBLK;
    int n0 = blockIdx.x * chunk;
    bool valid = (t < chunk) && (n0 + t < N);
    int v = valid ? indeg[n0 + t] : 0;
    sc[t] = v;
    __syncthreads();
    for (int ofs = 1; ofs < 256; ofs <<= 1) {
        int x = (t >= ofs) ? sc[t - ofs] : 0;
        __syncthreads();
        sc[t] += x;
        __syncthreads();
    }
    if (valid) {
        int excl = chunkBase[blockIdx.x] + sc[t] - v;
        dstbase[n0 + t] = excl;
        dpos[n0 + t] = excl;
    }
}

// ---------------- dst-sorted (src, rel) pairs ----------------
__global__ void k_dstscatter(const int* __restrict__ adjs, const int* __restrict__ rels, int E,
                             int* __restrict__ dpos, int2* __restrict__ srcrel) {
    int i = blockIdx.x * blockDim.x + threadIdx.x;
    int stride = gridDim.x * blockDim.x;
    for (; i < E; i += stride) {
        int dst = adjs[E + i];
        int p = atomicAdd(&dpos[dst], 1);
        srcrel[p] = make_int2(adjs[i], rels[i]);
    }
}

// ---------------- phase 1: aggc[n][b][k] = sum_{e->n} coef[r_e][b] * vb[src_e][k] ----------------
// one wave per node; lane l owns cols 2l, 2l+1 (one dword of the row).
__global__ void __launch_bounds__(256)
k_agg(const unsigned short* __restrict__ vb, const int2* __restrict__ srcrel,
      const int* __restrict__ dstbase, const float* __restrict__ coef,
      unsigned short* __restrict__ aggc, int N) {
    __shared__ float cs[RNUM * BNUM];
    int t = threadIdx.x;
    if (t < RNUM * BNUM) cs[t] = coef[t];
    __syncthreads();
    int wid = (blockIdx.x * 256 + t) >> 6;
    int lane = t & 63;
    if (wid >= N) return;
    int b0 = dstbase[wid], b1 = dstbase[wid + 1];
    const unsigned int* vbd = (const unsigned int*)vb;
    float a0_0 = 0, a0_1 = 0, a1_0 = 0, a1_1 = 0, a2_0 = 0, a2_1 = 0, a3_0 = 0, a3_1 = 0;
    float a4_0 = 0, a4_1 = 0, a5_0 = 0, a5_1 = 0, a6_0 = 0, a6_1 = 0, a7_0 = 0, a7_1 = 0;
    int p = b0;
    for (; p + 2 <= b1; p += 2) {
        int2 sr0 = srcrel[p];
        int2 sr1 = srcrel[p + 1];
        unsigned int u0 = vbd[(size_t)sr0.x * 64 + lane];
        unsigned int u1 = vbd[(size_t)sr1.x * 64 + lane];
        float4 cA0 = *(const float4*)&cs[sr0.y * 8];
        float4 cB0 = *(const float4*)&cs[sr0.y * 8 + 4];
        float4 cA1 = *(const float4*)&cs[sr1.y * 8];
        float4 cB1 = *(const float4*)&cs[sr1.y * 8 + 4];
        float v0 = bf2f((unsigned short)u0), v1 = bf2f((unsigned short)(u0 >> 16));
        float w0 = bf2f((unsigned short)u1), w1 = bf2f((unsigned short)(u1 >> 16));
        a0_0 += cA0.x * v0 + cA1.x * w0; a0_1 += cA0.x * v1 + cA1.x * w1;
        a1_0 += cA0.y * v0 + cA1.y * w0; a1_1 += cA0.y * v1 + cA1.y * w1;
        a2_0 += cA0.z * v0 + cA1.z * w0; a2_1 += cA0.z * v1 + cA1.z * w1;
        a3_0 += cA0.w * v0 + cA1.w * w0; a3_1 += cA0.w * v1 + cA1.w * w1;
        a4_0 += cB0.x * v0 + cB1.x * w0; a4_1 += cB0.x * v1 + cB1.x * w1;
        a5_0 += cB0.y * v0 + cB1.y * w0; a5_1 += cB0.y * v1 + cB1.y * w1;
        a6_0 += cB0.z * v0 + cB1.z * w0; a6_1 += cB0.z * v1 + cB1.z * w1;
        a7_0 += cB0.w * v0 + cB1.w * w0; a7_1 += cB0.w * v1 + cB1.w * w1;
    }
    if (p < b1) {
        int2 sr0 = srcrel[p];
        unsigned int u0 = vbd[(size_t)sr0.x * 64 + lane];
        float4 cA0 = *(const float4*)&cs[sr0.y * 8];
        float4 cB0 = *(const float4*)&cs[sr0.y * 8 + 4];
        float v0 = bf2f((unsigned short)u0), v1 = bf2f((unsigned short)(u0 >> 16));
        a0_0 += cA0.x * v0; a0_1 += cA0.x * v1;
        a1_0 += cA0.y * v0; a1_1 += cA0.y * v1;
        a2_0 += cA0.z * v0; a2_1 += cA0.z * v1;
        a3_0 += cA0.w * v0; a3_1 += cA0.w * v1;
        a4_0 += cB0.x * v0; a4_1 += cB0.x * v1;
        a5_0 += cB0.y * v0; a5_1 += cB0.y * v1;
        a6_0 += cB0.z * v0; a6_1 += cB0.z * v1;
        a7_0 += cB0.w * v0; a7_1 += cB0.w * v1;
    }
    unsigned int* ob = (unsigned int*)(aggc + (size_t)wid * 1024);
#define PACK(x, y) ((unsigned int)f2bf(x) | ((unsigned int)f2bf(y) << 16))
    ob[0 * 64 + lane] = PACK(a0_0, a0_1);
    ob[1 * 64 + lane] = PACK(a1_0, a1_1);
    ob[2 * 64 + lane] = PACK(a2_0, a2_1);
    ob[3 * 64 + lane] = PACK(a3_0, a3_1);
    ob[4 * 64 + lane] = PACK(a4_0, a4_1);
    ob[5 * 64 + lane] = PACK(a5_0, a5_1);
    ob[6 * 64 + lane] = PACK(a6_0, a6_1);
    ob[7 * 64 + lane] = PACK(a7_0, a7_1);
#undef PACK
}

// ---------------- phase 2: out = relu(aggc @ Wcat[0..7] + deg * (vb @ update)) ----------------
__global__ void __launch_bounds__(512)
k_gemm(const unsigned short* __restrict__ aggc, const unsigned short* __restrict__ vb,
       const unsigned short* __restrict__ wcatT, const int* __restrict__ dstbase,
       float* __restrict__ out, int N) {
    __shared__ unsigned short wt[D * D];      // 32 KB, per-segment staged
    __shared__ unsigned short at[32 * D];     // 8 KB
    int t = threadIdx.x;
    int lane = t & 63;
    int wave = t >> 6;
    int mtile = wave >> 2;
    int colbase = (wave & 3) << 5;
    int se = t >> 4;                  // row 0..31
    int skb = (t & 15) << 3;          // k-base
    int nb = blockIdx.x * 32;
    int nclamp = min(nb + se, N - 1);
    facc4 accA0 = {0, 0, 0, 0}, accA1 = {0, 0, 0, 0};
    facc4 accB0 = {0, 0, 0, 0}, accB1 = {0, 0, 0, 0};
    int eb = (mtile << 4) + (lane & 15);
    int c0 = colbase + (lane & 15);
    int c1 = c0 + 16;
    int wcol = t >> 4;                // 0..31
    int wkb = (t & 15) << 3;
    for (int s = 0; s < 9; ++s) {
        __syncthreads();
#pragma unroll
        for (int q = 0; q < 4; ++q) {
            int col = wcol + (q << 5);
            bfrag8 v = *(const bfrag8*)(wcatT + (size_t)s * 16384 + col * D + wkb);
            int byte = ((col << 8) + (wkb << 1)) ^ ((col & 7) << 4);
            *(bfrag8*)((char*)wt + byte) = v;
        }
        {
            const unsigned short* src = (s < 8)
                ? aggc + (size_t)nclamp * 1024 + s * D + skb
                : vb + (size_t)nclamp * D + skb;
            bfrag8 v = *(const bfrag8*)src;
            int byte = ((se << 8) + (skb << 1)) ^ ((se & 7) << 4);
            *(bfrag8*)((char*)at + byte) = v;
        }
        __syncthreads();
#pragma unroll
        for (int kk = 0; kk < 4; ++kk) {
            int kbase = (kk << 5) + ((lane >> 4) << 3);
            bfrag8 a = *(const bfrag8*)((char*)at + (((eb << 8) + (kbase << 1)) ^ ((eb & 7) << 4)));
            bfrag8 bv0 = *(const bfrag8*)((char*)wt + (((c0 << 8) + (kbase << 1)) ^ ((c0 & 7) << 4)));
            bfrag8 bv1 = *(const bfrag8*)((char*)wt + (((c1 << 8) + (kbase << 1)) ^ ((c1 & 7) << 4)));
            if (s < 8) {
                accA0 = __builtin_amdgcn_mfma_f32_16x16x32_bf16(a, bv0, accA0, 0, 0, 0);
                accA1 = __builtin_amdgcn_mfma_f32_16x16x32_bf16(a, bv1, accA1, 0, 0, 0);
            } else {
                accB0 = __builtin_amdgcn_mfma_f32_16x16x32_bf16(a, bv0, accB0, 0, 0, 0);
                accB1 = __builtin_amdgcn_mfma_f32_16x16x32_bf16(a, bv1, accB1, 0, 0, 0);
            }
        }
    }
    int ebase = (mtile << 4) + ((lane >> 4) << 2);
#pragma unroll
    for (int j = 0; j < 4; ++j) {
        int n = nb + ebase + j;
        if (n < N) {
            float deg = (float)(dstbase[n + 1] - dstbase[n]);
            float* q = out + (size_t)n * D + c0;
            q[0]  = fmaxf(accA0[j] + deg * accB0[j], 0.f);
            q[16] = fmaxf(accA1[j] + deg * accB1[j], 0.f);
        }
    }
}

// ================= fallback path (round-5 passing structure, used if ws too small) =================
__global__ void k_wrel(const float* __restrict__ comp, const float* __restrict__ weight,
                       float* __restrict__ wrel) {
    int idx = blockIdx.x * blockDim.x + threadIdx.x;
    int total = RNUM * D * D;
    int stride = gridDim.x * blockDim.x;
    for (; idx < total; idx += stride) {
        int r = idx >> 14;
        int rest = idx & 16383;
        float s = 0.f;
#pragma unroll
        for (int b = 0; b < BNUM; ++b) s += comp[r * BNUM + b] * weight[b * 16384 + rest];
        wrel[idx] = s;
    }
}

__global__ void k_hist(const int* __restrict__ adjs, const int* __restrict__ rels, int E,
                       int* __restrict__ blockHist, int* __restrict__ indeg) {
    __shared__ int h[4][RNUM];
    int t = threadIdx.x;
    if (t < 4 * RNUM) ((int*)h)[t] = 0;
    __syncthreads();
    int w = t >> 6;
    int chunk = (E + NBLK - 1) / NBLK;
    int start = blockIdx.x * chunk;
    int end = min(start + chunk, E);
    for (int i = start + t; i < end; i += 256) {
        atomicAdd(&h[w][rels[i]], 1);
        atomicAdd(&indeg[adjs[E + i]], 1);
    }
    __syncthreads();
    if (t < RNUM)
        blockHist[blockIdx.x * RNUM + t] = h[0][t] + h[1][t] + h[2][t] + h[3][t];
}

__global__ void k_prefix2(const int* __restrict__ blockHist, int* __restrict__ basep,
                          int* __restrict__ blockBase) {
    __shared__ int hist[NBLK * RNUM];
    __shared__ int pre[NBLK * RNUM];
    __shared__ int bp[RNUM + 1];
    int t = threadIdx.x;
    for (int i = t; i < NBLK * RNUM; i += 256) hist[i] = blockHist[i];
    __syncthreads();
    if (t < RNUM) {
        int s = 0;
        for (int b = 0; b < NBLK; ++b) {
            pre[b * RNUM + t] = s;
            s += hist[b * RNUM + t];
        }
        bp[t] = s;
    }
    __syncthreads();
    if (t == 0) {
        int s = 0;
        for (int r = 0; r < RNUM; ++r) {
            int c = bp[r];
            bp[r] = s;
            basep[r] = s;
            s += c;
        }
        bp[RNUM] = s;
        basep[RNUM] = s;
    }
    __syncthreads();
    for (int i = t; i < NBLK * RNUM; i += 256)
        blockBase[i] = pre[i] + bp[i & (RNUM - 1)];
}

__global__ void k_scatter2(const int* __restrict__ rels, int E,
                           const int* __restrict__ blockBase, int* __restrict__ sorted) {
    __shared__ int pos[RNUM];
    int t = threadIdx.x;
    if (t < RNUM) pos[t] = blockBase[blockIdx.x * RNUM + t];
    __syncthreads();
    int chunk = (E + NBLK - 1) / NBLK;
    int start = blockIdx.x * chunk;
    int end = min(start + chunk, E);
    for (int i = start + t; i < end; i += 256) {
        int p = atomicAdd(&pos[rels[i]], 1);
        sorted[p] = i;
    }
}

#define INIT_NODES 16
__global__ void k_init(const float* __restrict__ vfts, const float* __restrict__ update,
                       const int* __restrict__ indeg, float* __restrict__ out, int N) {
    __shared__ float upd[D * D];
    __shared__ float rows[INIT_NODES][APAD];
    int t = threadIdx.x;
    for (int idx = t; idx < D * D; idx += 256) upd[idx] = update[idx];
    int g = t >> 5;
    int cg = t & 31;
    for (int nb = blockIdx.x * INIT_NODES; nb < N; nb += gridDim.x * INIT_NODES) {
        __syncthreads();
        for (int idx = t; idx < INIT_NODES * D; idx += 256) {
            int nn = idx >> 7, k = idx & 127;
            int n = nb + nn;
            rows[nn][k] = (n < N) ? vfts[n * D + k] : 0.f;
        }
        __syncthreads();
        int n0 = g * 2, n1 = g * 2 + 1;
        float acc0[4] = {0, 0, 0, 0}, acc1[4] = {0, 0, 0, 0};
#pragma unroll 4
        for (int k = 0; k < D; ++k) {
            float4 w = *(const float4*)&upd[k * D + cg * 4];
            float a0 = rows[n0][k], a1 = rows[n1][k];
            acc0[0] += a0 * w.x; acc0[1] += a0 * w.y; acc0[2] += a0 * w.z; acc0[3] += a0 * w.w;
            acc1[0] += a1 * w.x; acc1[1] += a1 * w.y; acc1[2] += a1 * w.z; acc1[3] += a1 * w.w;
        }
        int na = nb + n0, nc = nb + n1;
        if (na < N) {
            float deg = (float)indeg[na];
            *(float4*)&out[na * D + cg * 4] =
                make_float4(deg * acc0[0], deg * acc0[1], deg * acc0[2], deg * acc0[3]);
        }
        if (nc < N) {
            float deg = (float)indeg[nc];
            *(float4*)&out[nc * D + cg * 4] =
                make_float4(deg * acc1[0], deg * acc1[1], deg * acc1[2], deg * acc1[3]);
        }
    }
}

__global__ void __launch_bounds__(512)
k_edge_at(const float* __restrict__ vfts, const int* __restrict__ adjs,
          const float* __restrict__ wrel, const float* __restrict__ alphas,
          const int* __restrict__ basep, const int* __restrict__ sorted,
          float* __restrict__ out, int E) {
    __shared__ unsigned short wt[D * D];
    __shared__ unsigned short at[EPB * D];
    __shared__ int esrc[EPB], edst[EPB];
    int t = threadIdx.x;
    int r = blockIdx.x / PPART;
    int bp = blockIdx.x % PPART;
    const float* wr = wrel + r * D * D;
    for (int i = t; i < D * D; i += 512) {
        int k = i >> 7, col = i & 127;
        int byte = (col << 8) + (k << 1);
        byte ^= (col & 7) << 4;
        *(unsigned short*)((char*)wt + byte) = f2bf(wr[i]);
    }
    float alpha = alphas[r];
    int s0 = basep[r], s1 = basep[r + 1];
    int lane = t & 63;
    int wave = t >> 6;
    int mtile = wave >> 2;
    int colbase = (wave & 3) << 5;
    int se = t >> 4;
    int skb = (t & 15) << 3;
    for (int off = s0 + bp * EPB; off < s1; off += PPART * EPB) {
        __syncthreads();
        if (t < EPB) {
            int idx = off + t;
            if (idx < s1) {
                int eid = sorted[idx];
                esrc[t] = adjs[eid];
                edst[t] = adjs[E + eid];
            } else {
                esrc[t] = 0;
                edst[t] = -1;
            }
        }
        __syncthreads();
        {
            const float* sp = vfts + (size_t)esrc[se] * D + skb;
            float4 f0 = *(const float4*)sp;
            float4 f1 = *(const float4*)(sp + 4);
            bfrag8 v;
            v[0] = (short)f2bf(f0.x); v[1] = (short)f2bf(f0.y);
            v[2] = (short)f2bf(f0.z); v[3] = (short)f2bf(f0.w);
            v[4] = (short)f2bf(f1.x); v[5] = (short)f2bf(f1.y);
            v[6] = (short)f2bf(f1.z); v[7] = (short)f2bf(f1.w);
            int byte = (se << 8) + (skb << 1);
            byte ^= (se & 7) << 4;
            *(bfrag8*)((char*)at + byte) = v;
        }
        __syncthreads();
        facc4 acc0 = {0.f, 0.f, 0.f, 0.f}, acc1 = {0.f, 0.f, 0.f, 0.f};
        int eb = (mtile << 4) + (lane & 15);
        int c0 = colbase + (lane & 15);
        int c1 = c0 + 16;
#pragma unroll
        for (int kk = 0; kk < 4; ++kk) {
            int kbase = (kk << 5) + ((lane >> 4) << 3);
            int ab = ((eb << 8) + (kbase << 1)) ^ ((eb & 7) << 4);
            bfrag8 a = *(const bfrag8*)((char*)at + ab);
            int b0 = ((c0 << 8) + (kbase << 1)) ^ ((c0 & 7) << 4);
            bfrag8 bv0 = *(const bfrag8*)((char*)wt + b0);
            int b1 = ((c1 << 8) + (kbase << 1)) ^ ((c1 & 7) << 4);
            bfrag8 bv1 = *(const bfrag8*)((char*)wt + b1);
            acc0 = __builtin_amdgcn_mfma_f32_16x16x32_bf16(a, bv0, acc0, 0, 0, 0);
            acc1 = __builtin_amdgcn_mfma_f32_16x16x32_bf16(a, bv1, acc1, 0, 0, 0);
        }
        int ebase = (mtile << 4) + ((lane >> 4) << 2);
#pragma unroll
        for (int j = 0; j < 4; ++j) {
            int d = edst[ebase + j];
            if (d >= 0) {
                float* p = out + (size_t)d * D + c0;
                atomicAdd(p, alpha * acc0[j]);
                atomicAdd(p + 16, alpha * acc1[j]);
            }
        }
    }
}

__global__ void k_relu(float* __restrict__ out, int total4) {
    int i = blockIdx.x * blockDim.x + threadIdx.x;
    int stride = gridDim.x * blockDim.x;
    for (; i < total4; i += stride) {
        float4 v = ((float4*)out)[i];
        v.x = fmaxf(v.x, 0.f);
        v.y = fmaxf(v.y, 0.f);
        v.z = fmaxf(v.z, 0.f);
        v.w = fmaxf(v.w, 0.f);
        ((float4*)out)[i] = v;
    }
}

extern "C" void kernel_launch(void* const* d_in, const int* in_sizes, int n_in,
                              void* d_out, int out_size, void* d_ws, size_t ws_size,
                              hipStream_t stream) {
    const float* vfts   = (const float*)d_in[0];
    const int*   adjs   = (const int*)d_in[1];
    const int*   rels   = (const int*)d_in[2];
    const float* er     = (const float*)d_in[3];
    const float* ert    = (const float*)d_in[4];
    const float* weight = (const float*)d_in[5];
    const float* comp   = (const float*)d_in[6];
    const float* w1     = (const float*)d_in[7];
    const float* b1     = (const float*)d_in[8];
    const float* w2     = (const float*)d_in[9];
    const float* b2     = (const float*)d_in[10];
    const float* update = (const float*)d_in[11];
    float* out = (float*)d_out;

    int N = in_sizes[0] / D;
    int E = in_sizes[2];
    int Nr = (N + 63) & ~63;

    char* ws = (char*)d_ws;
    // --- new-path layout ---
    size_t o = 0;
    float* alphas = (float*)(ws + o);                    o += 256;
    float* coef   = (float*)(ws + o);                    o += 512 + 256;
    unsigned short* vb = (unsigned short*)(ws + o);      o += (size_t)N * D * 2;       // 12.8 MB
    o = (o + 255) & ~(size_t)255;
    unsigned short* aggc = (unsigned short*)(ws + o);    o += (size_t)N * 1024 * 2;    // 102.4 MB
    o = (o + 255) & ~(size_t)255;
    unsigned short* wcatT = (unsigned short*)(ws + o);   o += (size_t)9 * D * D * 2;   // 0.3 MB
    o = (o + 255) & ~(size_t)255;
    int2* srcrel   = (int2*)(ws + o);                    o += (size_t)E * 8;           // 3.2 MB
    int* indeg     = (int*)(ws + o);                     o += (size_t)Nr * 4;
    int* dstbase   = (int*)(ws + o);                     o += (size_t)(Nr + 64) * 4;
    int* dpos      = (int*)(ws + o);                     o += (size_t)Nr * 4;
    int* chunkSum  = (int*)(ws + o);                     o += NBLK * 4;
    int* chunkBase = (int*)(ws + o);                     o += NBLK * 4;
    bool big = (o <= ws_size);

    if (big) {
        hipMemsetAsync(indeg, 0, (size_t)Nr * 4, stream);
        k_alphas<<<RNUM, D, 0, stream>>>(vfts, adjs, er, ert, w1, b1, w2, b2, alphas, E);
        k_coef<<<1, 128, 0, stream>>>(alphas, comp, coef);
        k_prep<<<1024, 256, 0, stream>>>(vfts, vb, N * D / 8);
        k_wcat<<<256, 256, 0, stream>>>(weight, update, wcatT);
        k_indeg<<<256, 256, 0, stream>>>(adjs, E, indeg);
        k_scanA<<<NBLK, 256, 0, stream>>>(indeg, N, chunkSum);
        k_scanB<<<1, 64, 0, stream>>>(chunkSum, chunkBase, dstbase, N);
        k_scanC<<<NBLK, 256, 0, stream>>>(indeg, N, chunkBase, dstbase, dpos);
        k_dstscatter<<<256, 256, 0, stream>>>(adjs, rels, E, dpos, srcrel);
        k_agg<<<(N * 64 + 255) / 256, 256, 0, stream>>>(vb, srcrel, dstbase, coef, aggc, N);
        k_gemm<<<(N + 31) / 32, 512, 0, stream>>>(aggc, vb, wcatT, dstbase, out, N);
    } else {
        // fallback: round-5 passing layout (atomic scatter)
        float* fwrel   = (float*)ws;
        float* falphas = (float*)(ws + (1 << 20));
        int* ib = (int*)(ws + (1 << 20) + 256);
        int* fbasep     = ib;
        int* findeg     = ib + 32;
        int* fblockHist = findeg + Nr;
        int* fblockBase = fblockHist + NBLK * RNUM;
        int* fsorted    = fblockBase + NBLK * RNUM;

        hipMemsetAsync(findeg, 0, (size_t)Nr * 4, stream);
        k_wrel<<<256, 256, 0, stream>>>(comp, weight, fwrel);
        k_alphas<<<RNUM, D, 0, stream>>>(vfts, adjs, er, ert, w1, b1, w2, b2, falphas, E);
        k_hist<<<NBLK, 256, 0, stream>>>(adjs, rels, E, fblockHist, findeg);
        k_prefix2<<<1, 256, 0, stream>>>(fblockHist, fbasep, fblockBase);
        k_scatter2<<<NBLK, 256, 0, stream>>>(rels, E, fblockBase, fsorted);
        k_init<<<512, 256, 0, stream>>>(vfts, update, findeg, out, N);
        k_edge_at<<<RNUM * PPART, 512, 0, stream>>>(vfts, adjs, fwrel, falphas, fbasep,
                                                    fsorted, out, E);
        k_relu<<<512, 256, 0, stream>>>(out, N * D / 4);
    }
}